// Round 1
// baseline (16781.563 us; speedup 1.0000x reference)
//
#include <hip/hip_runtime.h>
#include <cstddef>
#include <cstdint>

#define BM 64
#define BN 64
#define BK 32

__device__ __forceinline__ float gelu_tanh(float x) {
  float x3 = x * x * x;
  float t = tanhf(0.7978845608028654f * (x + 0.044715f * x3));
  return 0.5f * x * (1.0f + t);
}
__device__ __forceinline__ float softplus_f(float x) {
  return (x > 20.0f) ? x : log1pf(expf(x));
}

// ---------------- encoder: patch-embed GEMM ----------------
// A: gathered 16x16 patches of x (rows = frame*256+pix, K=1024 = c*256+ph*16+pw)
// W: enc_w (768 x 1024) row-major (N-major) -> transposed gather into LDS
// out: zr/zi pixel-major [row][384]
__global__ __launch_bounds__(256) void encoder_kernel(
    const float* __restrict__ x, const float* __restrict__ ew,
    const float* __restrict__ eb, float* __restrict__ zr, float* __restrict__ zi) {
  __shared__ float As[BK][BM];
  __shared__ float Ws[BK][BN];
  const int m0 = blockIdx.x * BM;
  const int o0 = blockIdx.y * BN;
  const int tid = threadIdx.x;
  const int tn = tid & 15, tm = tid >> 4;
  float acc[4][4] = {};
  for (int k0 = 0; k0 < 1024; k0 += BK) {
    for (int s = tid; s < 512; s += 256) {
      {
        int r = s >> 3, kk = (s & 7) << 2;
        int row = m0 + r;
        int frame = row >> 8, pix = row & 255;
        int h = pix >> 4, w = pix & 15;
        int k = k0 + kk;
        int c = k >> 8, rem = k & 255;
        int ph = rem >> 4, pw = rem & 15;
        const float4 v = *(const float4*)(x + (((size_t)(frame * 4 + c) * 256 + h * 16 + ph) * 256 + w * 16 + pw));
        As[kk + 0][r] = v.x; As[kk + 1][r] = v.y; As[kk + 2][r] = v.z; As[kk + 3][r] = v.w;
      }
      {
        int oo = s >> 3, kk = (s & 7) << 2;
        const float4 v = *(const float4*)(ew + (size_t)(o0 + oo) * 1024 + k0 + kk);
        Ws[kk + 0][oo] = v.x; Ws[kk + 1][oo] = v.y; Ws[kk + 2][oo] = v.z; Ws[kk + 3][oo] = v.w;
      }
    }
    __syncthreads();
#pragma unroll
    for (int kk = 0; kk < BK; ++kk) {
      float4 a4 = *(const float4*)&As[kk][tm << 2];
      float4 w4 = *(const float4*)&Ws[kk][tn << 2];
      float a[4] = {a4.x, a4.y, a4.z, a4.w};
      float w[4] = {w4.x, w4.y, w4.z, w4.w};
#pragma unroll
      for (int i = 0; i < 4; ++i)
#pragma unroll
        for (int j = 0; j < 4; ++j) acc[i][j] = fmaf(a[i], w[j], acc[i][j]);
    }
    __syncthreads();
  }
#pragma unroll
  for (int i = 0; i < 4; ++i) {
    int row = m0 + (tm << 2) + i;
#pragma unroll
    for (int j = 0; j < 4; ++j) {
      int o = o0 + (tn << 2) + j;
      float v = acc[i][j] + eb[o];
      if (o < 384) zr[(size_t)row * 384 + o] = v;
      else         zi[(size_t)row * 384 + o - 384] = v;
    }
  }
}

// ---------------- conv weight transpose: (o,c,tap) -> wT[tap][c][o] ----------------
__global__ __launch_bounds__(256) void transpose_cw_kernel(
    const float* __restrict__ cwl, float* __restrict__ wT) {
  __shared__ float tile[64][65];
  const int c0 = blockIdx.x * 64, o0 = blockIdx.y * 64, tap = blockIdx.z;
  const int t = threadIdx.x;
  const int cc = t & 63, q = t >> 6;
  for (int k = 0; k < 16; ++k) {
    int oo = q * 16 + k;
    tile[cc][oo] = cwl[((size_t)(o0 + oo) * 768 + (c0 + cc)) * 9 + tap];
  }
  __syncthreads();
  const int oo2 = t & 63, q2 = t >> 6;
  for (int k = 0; k < 16; ++k) {
    int cc2 = q2 * 16 + k;
    wT[((size_t)tap * 768 + c0 + cc2) * 768 + o0 + oo2] = tile[cc2][oo2];
  }
}

// ---------------- LayerNorm over 768 = concat(re[384], im[384]) ----------------
__global__ __launch_bounds__(256) void ln_kernel(
    const float* __restrict__ inr, const float* __restrict__ ini,
    const float* __restrict__ g, const float* __restrict__ b,
    float* __restrict__ outr, float* __restrict__ outi) {
  const int row = blockIdx.x;
  const int tid = threadIdx.x;
  float v[3];
#pragma unroll
  for (int j = 0; j < 3; ++j) {
    int c = tid + j * 256;
    v[j] = (c < 384) ? inr[(size_t)row * 384 + c] : ini[(size_t)row * 384 + c - 384];
  }
  float s = v[0] + v[1] + v[2];
  float q = v[0] * v[0] + v[1] * v[1] + v[2] * v[2];
#pragma unroll
  for (int off = 32; off > 0; off >>= 1) {
    s += __shfl_down(s, off);
    q += __shfl_down(q, off);
  }
  __shared__ float rs[4], rq[4];
  __shared__ float s_mean, s_inv;
  int wv = tid >> 6;
  if ((tid & 63) == 0) { rs[wv] = s; rq[wv] = q; }
  __syncthreads();
  if (tid == 0) {
    float S = rs[0] + rs[1] + rs[2] + rs[3];
    float Q = rq[0] + rq[1] + rq[2] + rq[3];
    float mean = S * (1.0f / 768.0f);
    float var = Q * (1.0f / 768.0f) - mean * mean;
    s_mean = mean;
    s_inv = rsqrtf(var + 1e-5f);
  }
  __syncthreads();
  float mean = s_mean, inv = s_inv;
#pragma unroll
  for (int j = 0; j < 3; ++j) {
    int c = tid + j * 256;
    float o = (v[j] - mean) * inv * g[c] + b[c];
    if (c < 384) outr[(size_t)row * 384 + c] = o;
    else         outi[(size_t)row * 384 + c - 384] = o;
  }
}

// ---------------- 3x3 SAME conv as implicit GEMM; epilogue: z += conv + bias ----------------
__global__ __launch_bounds__(256) void conv3x3_kernel(
    const float* __restrict__ xnr, const float* __restrict__ xni,
    const float* __restrict__ wT, const float* __restrict__ cbias,
    float* __restrict__ zr, float* __restrict__ zi) {
  __shared__ float As[BK][BM];
  __shared__ float Ws[BK][BN];
  const int m0 = blockIdx.x * BM;       // pixel base within frame
  const int o0 = blockIdx.y * BN;       // out-channel base (0..767)
  const int frame = blockIdx.z;
  const int tid = threadIdx.x;
  const int tn = tid & 15, tm = tid >> 4;
  float acc[4][4] = {};
  for (int tap = 0; tap < 9; ++tap) {
    const int dy = tap / 3 - 1, dx = tap % 3 - 1;
    for (int kc = 0; kc < 24; ++kc) {
      const float* pl = (kc < 12) ? xnr : xni;
      const int cb0 = (kc % 12) * 32;   // channel base within plane
      const int cg0 = kc * 32;          // global channel base for weights
      for (int s = tid; s < 512; s += 256) {
        {
          int r = s >> 3, kk = (s & 7) << 2;
          int pix = m0 + r;
          int h = (pix >> 4) + dy, w = (pix & 15) + dx;
          float4 v = {0.f, 0.f, 0.f, 0.f};
          if ((unsigned)h < 16u && (unsigned)w < 16u)
            v = *(const float4*)(pl + ((size_t)frame * 256 + h * 16 + w) * 384 + cb0 + kk);
          As[kk + 0][r] = v.x; As[kk + 1][r] = v.y; As[kk + 2][r] = v.z; As[kk + 3][r] = v.w;
        }
        {
          int wr_ = s >> 4, wc = (s & 15) << 2;
          *(float4*)&Ws[wr_][wc] = *(const float4*)(wT + ((size_t)tap * 768 + cg0 + wr_) * 768 + o0 + wc);
        }
      }
      __syncthreads();
#pragma unroll
      for (int kk = 0; kk < BK; ++kk) {
        float4 a4 = *(const float4*)&As[kk][tm << 2];
        float4 w4 = *(const float4*)&Ws[kk][tn << 2];
        float a[4] = {a4.x, a4.y, a4.z, a4.w};
        float w[4] = {w4.x, w4.y, w4.z, w4.w};
#pragma unroll
        for (int i = 0; i < 4; ++i)
#pragma unroll
          for (int j = 0; j < 4; ++j) acc[i][j] = fmaf(a[i], w[j], acc[i][j]);
      }
      __syncthreads();
    }
  }
#pragma unroll
  for (int i = 0; i < 4; ++i) {
    int pix = m0 + (tm << 2) + i;
    size_t base = ((size_t)frame * 256 + pix) * 384;
#pragma unroll
    for (int j = 0; j < 4; ++j) {
      int o = o0 + (tn << 2) + j;
      float v = acc[i][j] + cbias[o];
      if (o < 384) zr[base + o] += v;
      else         zi[base + o - 384] += v;
    }
  }
}

// ---------------- generic complex GEMM: C = A(MxK) * W(KxN) ----------------
template <bool GELU, bool ACCUM>
__global__ __launch_bounds__(256) void cgemm_kernel(
    const float* __restrict__ Ar, const float* __restrict__ Ai, int lda,
    const float* __restrict__ Wr, const float* __restrict__ Wi, int ldw,
    float* __restrict__ Cr, float* __restrict__ Ci, int ldc, int M, int K) {
  __shared__ float Asr[BK][BM], Asi[BK][BM];
  __shared__ float Wsr[BK][BN], Wsi[BK][BN];
  const int m0 = blockIdx.x * BM;
  const int n0 = blockIdx.y * BN;
  const int tid = threadIdx.x;
  const int tn = tid & 15, tm = tid >> 4;
  float accr[4][4] = {}, acci[4][4] = {};
  for (int k0 = 0; k0 < K; k0 += BK) {
    for (int s = tid; s < 512; s += 256) {
      {
        int r = s >> 3, kk = (s & 7) << 2;
        int row = m0 + r;
        float4 vr = {0.f, 0.f, 0.f, 0.f}, vi = {0.f, 0.f, 0.f, 0.f};
        if (row < M) {
          vr = *(const float4*)(Ar + (size_t)row * lda + k0 + kk);
          vi = *(const float4*)(Ai + (size_t)row * lda + k0 + kk);
        }
        Asr[kk + 0][r] = vr.x; Asr[kk + 1][r] = vr.y; Asr[kk + 2][r] = vr.z; Asr[kk + 3][r] = vr.w;
        Asi[kk + 0][r] = vi.x; Asi[kk + 1][r] = vi.y; Asi[kk + 2][r] = vi.z; Asi[kk + 3][r] = vi.w;
      }
      {
        int wr_ = s >> 4, wc = (s & 15) << 2;
        *(float4*)&Wsr[wr_][wc] = *(const float4*)(Wr + (size_t)(k0 + wr_) * ldw + n0 + wc);
        *(float4*)&Wsi[wr_][wc] = *(const float4*)(Wi + (size_t)(k0 + wr_) * ldw + n0 + wc);
      }
    }
    __syncthreads();
#pragma unroll
    for (int kk = 0; kk < BK; ++kk) {
      float4 ar4 = *(const float4*)&Asr[kk][tm << 2];
      float4 ai4 = *(const float4*)&Asi[kk][tm << 2];
      float4 wr4 = *(const float4*)&Wsr[kk][tn << 2];
      float4 wi4 = *(const float4*)&Wsi[kk][tn << 2];
      float ar[4] = {ar4.x, ar4.y, ar4.z, ar4.w};
      float ai[4] = {ai4.x, ai4.y, ai4.z, ai4.w};
      float wr[4] = {wr4.x, wr4.y, wr4.z, wr4.w};
      float wi[4] = {wi4.x, wi4.y, wi4.z, wi4.w};
#pragma unroll
      for (int i = 0; i < 4; ++i)
#pragma unroll
        for (int j = 0; j < 4; ++j) {
          accr[i][j] = fmaf(ar[i], wr[j], accr[i][j]);
          accr[i][j] = fmaf(-ai[i], wi[j], accr[i][j]);
          acci[i][j] = fmaf(ar[i], wi[j], acci[i][j]);
          acci[i][j] = fmaf(ai[i], wr[j], acci[i][j]);
        }
    }
    __syncthreads();
  }
#pragma unroll
  for (int i = 0; i < 4; ++i) {
    int row = m0 + (tm << 2) + i;
    if (row >= M) continue;
#pragma unroll
    for (int j = 0; j < 4; ++j) {
      int col = n0 + (tn << 2) + j;
      float vr = accr[i][j], vi = acci[i][j];
      if (GELU) { vr = gelu_tanh(vr); vi = gelu_tanh(vi); }
      size_t idx = (size_t)row * ldc + col;
      if (ACCUM) { Cr[idx] += vr; Ci[idx] += vi; }
      else       { Cr[idx] = vr;  Ci[idx] = vi; }
    }
  }
}

// ---------------- mean over 256 pixels ----------------
__global__ __launch_bounds__(384) void mean_kernel(
    const float* __restrict__ eigr, const float* __restrict__ eigi,
    float* __restrict__ mr, float* __restrict__ mi) {
  const int frame = blockIdx.x;
  const int d = threadIdx.x;
  const float* in = blockIdx.y ? eigi : eigr;
  float* out = blockIdx.y ? mi : mr;
  const float* p = in + (size_t)frame * 256 * 384 + d;
  float s = 0.f;
#pragma unroll 4
  for (int px = 0; px < 256; ++px) s += p[(size_t)px * 384];
  out[frame * 384 + d] = s * (1.0f / 256.0f);
}

// ---------------- flux scan + per-(b,t,d) operator precompute ----------------
__global__ __launch_bounds__(384) void flux_kernel(
    const float* __restrict__ dt, const float* __restrict__ lamf,
    const float* __restrict__ nu, const float* __restrict__ omega,
    const float* __restrict__ mr, const float* __restrict__ mi,
    float* __restrict__ fluxr, float* __restrict__ fluxi,
    float* __restrict__ opdr, float* __restrict__ opdi,
    float* __restrict__ opfr, float* __restrict__ opfi) {
  const int b = blockIdx.x;
  const int d = threadIdx.x;
  const float sp = softplus_f(lamf[d]);
  float lre = -softplus_f(nu[d]);
  lre = fmaxf(lre, -5.0f);  // clip(-sp, -5, 0.3): upper bound inert (lre <= 0)
  const float lim = omega[d];
  const float den = lre * lre + lim * lim;
  float fr = 0.f, fi = 0.f;
  for (int t = 0; t < 12; ++t) {
    const float dtv = dt[b * 12 + t];
    const int idx = (b * 12 + t) * 384 + d;
    const float A = expf(-sp * dtv);
    fr = A * fr + mr[idx] * dtv;
    fi = A * fi + mi[idx] * dtv;
    fluxr[idx] = fr; fluxi[idx] = fi;
    const float ed = expf(lre * dtv);
    const float odr = ed * cosf(lim * dtv);
    const float odi = ed * sinf(lim * dtv);
    opdr[idx] = odr; opdi[idx] = odi;
    const float nr_ = odr - 1.0f, ni_ = odi;
    opfr[idx] = (nr_ * lre + ni_ * lim) / den;
    opfi[idx] = (ni_ * lre - nr_ * lim) / den;
  }
}

// ---------------- forcing + u_t (in-place on eig) ----------------
__global__ __launch_bounds__(256) void forcing_kernel(
    float* __restrict__ eigr, float* __restrict__ eigi,
    const float* __restrict__ fluxr,
    const float* __restrict__ srcr, const float* __restrict__ srci,
    const float* __restrict__ Wg,
    const float* __restrict__ opfr, const float* __restrict__ opfi, int total) {
  const int g = blockIdx.x * 256 + threadIdx.x;
  if (g >= total) return;
  const int d = g % 384;
  const int fp = g / 384;          // frame*256+pix
  const int fidx = (fp >> 8) * 384 + d;
  const float gate = 1.0f / (1.0f + expf(-fluxr[fidx] * Wg[d]));
  const float er = eigr[g], ei = eigi[g];
  const float fr = er * gate + srcr[fidx] * (1.0f - gate);
  const float fi = ei * gate + srci[fidx] * (1.0f - gate);
  const float pr = opfr[fidx], pi = opfi[fidx];
  eigr[g] = fr * pr - fi * pi;
  eigi[g] = fr * pi + fi * pr;
}

// ---------------- u_out pscan over T (in-place) ----------------
__global__ __launch_bounds__(256) void pscan_u_kernel(
    float* __restrict__ eigr, float* __restrict__ eigi,
    const float* __restrict__ opdr, const float* __restrict__ opdi) {
  const int g = blockIdx.x * 256 + threadIdx.x;
  if (g >= 4 * 256 * 384) return;
  const int d = g % 384;
  const int pix = (g / 384) & 255;
  const int b = g / (384 * 256);
  float ur = 0.f, ui = 0.f;
  for (int t = 0; t < 12; ++t) {
    const int frame = b * 12 + t;
    const size_t idx = ((size_t)frame * 256 + pix) * 384 + d;
    const int fidx = frame * 384 + d;
    const float ar = opdr[fidx], ai = opdi[fidx];
    const float nr = ar * ur - ai * ui + eigr[idx];
    const float ni = ar * ui + ai * ur + eigi[idx];
    eigr[idx] = nr; eigi[idx] = ni;
    ur = nr; ui = ni;
  }
}

// ---------------- z += df ----------------
__global__ __launch_bounds__(256) void add_df_kernel(
    float* __restrict__ zr, float* __restrict__ zi,
    const float* __restrict__ dfr, const float* __restrict__ dfi, int n) {
  const int g = blockIdx.x * 256 + threadIdx.x;
  if (g < n) { zr[g] += dfr[g]; zi[g] += dfi[g]; }
}

// ---------------- decoder GEMM + patch scatter ----------------
__global__ __launch_bounds__(256) void decoder_kernel(
    const float* __restrict__ zr, const float* __restrict__ zi,
    const float* __restrict__ dw, const float* __restrict__ db,
    float* __restrict__ out) {
  __shared__ float As[BK][BM];
  __shared__ float Ws[BK][BN];
  const int m0 = blockIdx.x * BM;
  const int o0 = blockIdx.y * BN;
  const int tid = threadIdx.x;
  const int tn = tid & 15, tm = tid >> 4;
  float acc[4][4] = {};
  for (int k0 = 0; k0 < 768; k0 += BK) {
    for (int s = tid; s < 512; s += 256) {
      {
        int r = s >> 3, kk = (s & 7) << 2;
        int row = m0 + r;
        int k = k0 + kk;
        const float* pl = (k < 384) ? zr : zi;
        int kc = (k < 384) ? k : k - 384;
        const float4 v = *(const float4*)(pl + (size_t)row * 384 + kc);
        As[kk + 0][r] = v.x; As[kk + 1][r] = v.y; As[kk + 2][r] = v.z; As[kk + 3][r] = v.w;
      }
      {
        int oo = s >> 3, kk = (s & 7) << 2;
        const float4 v = *(const float4*)(dw + (size_t)(o0 + oo) * 768 + k0 + kk);
        Ws[kk + 0][oo] = v.x; Ws[kk + 1][oo] = v.y; Ws[kk + 2][oo] = v.z; Ws[kk + 3][oo] = v.w;
      }
    }
    __syncthreads();
#pragma unroll
    for (int kk = 0; kk < BK; ++kk) {
      float4 a4 = *(const float4*)&As[kk][tm << 2];
      float4 w4 = *(const float4*)&Ws[kk][tn << 2];
      float a[4] = {a4.x, a4.y, a4.z, a4.w};
      float w[4] = {w4.x, w4.y, w4.z, w4.w};
#pragma unroll
      for (int i = 0; i < 4; ++i)
#pragma unroll
        for (int j = 0; j < 4; ++j) acc[i][j] = fmaf(a[i], w[j], acc[i][j]);
    }
    __syncthreads();
  }
#pragma unroll
  for (int i = 0; i < 4; ++i) {
    int row = m0 + (tm << 2) + i;
    int frame = row >> 8, pix = row & 255;
    int hp = pix >> 4, wp = pix & 15;
#pragma unroll
    for (int j = 0; j < 4; ++j) {
      int o = o0 + (tn << 2) + j;
      int co = o >> 8, p1 = (o >> 4) & 15, p2 = o & 15;
      out[(((size_t)frame * 4 + co) * 256 + hp * 16 + p1) * 256 + wp * 16 + p2] = acc[i][j] + db[o];
    }
  }
}

extern "C" void kernel_launch(void* const* d_in, const int* in_sizes, int n_in,
                              void* d_out, int out_size, void* d_ws, size_t ws_size,
                              hipStream_t stream) {
  const float* x        = (const float*)d_in[0];
  const float* dt       = (const float*)d_in[1];
  const float* enc_w    = (const float*)d_in[2];
  const float* enc_b    = (const float*)d_in[3];
  const float* ns_g     = (const float*)d_in[4];
  const float* ns_b     = (const float*)d_in[5];
  const float* cw       = (const float*)d_in[6];
  const float* cb       = (const float*)d_in[7];
  const float* nt_g     = (const float*)d_in[8];
  const float* nt_b     = (const float*)d_in[9];
  const float* E_re     = (const float*)d_in[10];
  const float* E_im     = (const float*)d_in[11];
  const float* Ei_re    = (const float*)d_in[12];
  const float* Ei_im    = (const float*)d_in[13];
  const float* lam_flux = (const float*)d_in[14];
  const float* Ws_re    = (const float*)d_in[15];
  const float* Ws_im    = (const float*)d_in[16];
  const float* Wg       = (const float*)d_in[17];
  const float* nu       = (const float*)d_in[18];
  const float* omega    = (const float*)d_in[19];
  const float* w1_re    = (const float*)d_in[20];
  const float* w1_im    = (const float*)d_in[21];
  const float* w2_re    = (const float*)d_in[22];
  const float* w2_im    = (const float*)d_in[23];
  const float* dec_w    = (const float*)d_in[24];
  const float* dec_b    = (const float*)d_in[25];
  float* out = (float*)d_out;

  const size_t NP = 48ull * 256 * 384;   // 4,718,592 per plane
  const size_t WT = 9ull * 768 * 768;    // 5,308,416
  const size_t SM = 48ull * 384;         // 18,432
  const size_t need = (8 * NP + WT + 10 * SM) * sizeof(float);
  if (ws_size < need) return;  // workspace insufficient — bail (bench will flag)

  float* ws   = (float*)d_ws;
  float* zr   = ws;
  float* zi   = zr + NP;
  float* xnr  = zi + NP;
  float* xni  = xnr + NP;
  float* eigr = xni + NP;
  float* eigi = eigr + NP;
  float* dfr  = eigi + NP;
  float* dfi  = dfr + NP;
  float* wT   = dfi + NP;
  float* sm   = wT + WT;
  float* mr    = sm;            float* mi    = mr + SM;
  float* fluxr = mi + SM;       float* fluxi = fluxr + SM;
  float* opdr  = fluxi + SM;    float* opdi  = opdr + SM;
  float* opfr  = opdi + SM;     float* opfi  = opfr + SM;
  float* srcr  = opfi + SM;     float* srci  = srcr + SM;

  // FFN h1 chunk buffers overlay eig (dead after decoded GEMM) and df (dead after z+=df)
  float* h1r = eigr;  // spans eigr..eigi  = 2*NP = 12288*768
  float* h1i = dfr;   // spans dfr..dfi    = 2*NP

  encoder_kernel<<<dim3(192, 12), 256, 0, stream>>>(x, enc_w, enc_b, zr, zi);

  for (int l = 0; l < 4; ++l) {
    const float* cwl = cw + (size_t)l * 768 * 768 * 9;
    transpose_cw_kernel<<<dim3(12, 12, 9), 256, 0, stream>>>(cwl, wT);
    ln_kernel<<<12288, 256, 0, stream>>>(zr, zi, ns_g + l * 768, ns_b + l * 768, xnr, xni);
    conv3x3_kernel<<<dim3(4, 12, 48), 256, 0, stream>>>(xnr, xni, wT, cb + l * 768, zr, zi);
    cgemm_kernel<false, false><<<dim3(192, 6), 256, 0, stream>>>(
        zr, zi, 384, E_re + (size_t)l * 384 * 384, E_im + (size_t)l * 384 * 384, 384,
        eigr, eigi, 384, 12288, 384);
    mean_kernel<<<dim3(48, 2), 384, 0, stream>>>(eigr, eigi, mr, mi);
    flux_kernel<<<4, 384, 0, stream>>>(dt, lam_flux + l * 384, nu + l * 384, omega + l * 384,
                                       mr, mi, fluxr, fluxi, opdr, opdi, opfr, opfi);
    cgemm_kernel<false, false><<<dim3(1, 6), 256, 0, stream>>>(
        fluxr, fluxi, 384, Ws_re + (size_t)l * 384 * 384, Ws_im + (size_t)l * 384 * 384, 384,
        srcr, srci, 384, 48, 384);
    forcing_kernel<<<(int)((NP + 255) / 256), 256, 0, stream>>>(
        eigr, eigi, fluxr, srcr, srci, Wg + l * 384, opfr, opfi, (int)NP);
    pscan_u_kernel<<<1536, 256, 0, stream>>>(eigr, eigi, opdr, opdi);
    cgemm_kernel<false, false><<<dim3(192, 6), 256, 0, stream>>>(
        eigr, eigi, 384, Ei_re + (size_t)l * 384 * 384, Ei_im + (size_t)l * 384 * 384, 384,
        dfr, dfi, 384, 12288, 384);
    ln_kernel<<<12288, 256, 0, stream>>>(dfr, dfi, nt_g + l * 768, nt_b + l * 768, xnr, xni);
    add_df_kernel<<<(int)((NP + 255) / 256), 256, 0, stream>>>(zr, zi, dfr, dfi, (int)NP);
    for (int ch = 0; ch < 2; ++ch) {
      cgemm_kernel<true, false><<<dim3(192, 12), 256, 0, stream>>>(
          xnr, xni, 384,
          w1_re + (size_t)l * 384 * 1536 + ch * 768, w1_im + (size_t)l * 384 * 1536 + ch * 768, 1536,
          h1r, h1i, 768, 12288, 384);
      cgemm_kernel<false, true><<<dim3(192, 6), 256, 0, stream>>>(
          h1r, h1i, 768,
          w2_re + (size_t)l * 1536 * 384 + (size_t)ch * 768 * 384,
          w2_im + (size_t)l * 1536 * 384 + (size_t)ch * 768 * 384, 384,
          zr, zi, 384, 12288, 768);
    }
  }

  decoder_kernel<<<dim3(192, 16), 256, 0, stream>>>(zr, zi, dec_w, dec_b, out);
}

// Round 2
// 4074.666 us; speedup vs baseline: 4.1185x; 4.1185x over previous
//
#include <hip/hip_runtime.h>
#include <cstddef>
#include <cstdint>

typedef unsigned short u16;
typedef short bf16x8 __attribute__((ext_vector_type(8)));
typedef float f32x4 __attribute__((ext_vector_type(4)));

#define BM 64
#define BN 64
#define BK 32
#define LDA_S 40   // padded LDS row length in bf16 elements (80 B)

__device__ __forceinline__ float gelu_tanh(float x) {
  float x3 = x * x * x;
  float t = tanhf(0.7978845608028654f * (x + 0.044715f * x3));
  return 0.5f * x * (1.0f + t);
}
__device__ __forceinline__ float softplus_f(float x) {
  return (x > 20.0f) ? x : log1pf(expf(x));
}
__device__ __forceinline__ u16 f2bf(float f) {
  uint32_t u = __float_as_uint(f);
  uint32_t r = (u + 0x7fffu + ((u >> 16) & 1u)) >> 16;
  return (u16)r;
}
__device__ __forceinline__ bf16x8 neg8(bf16x8 v) {
  bf16x8 r;
#pragma unroll
  for (int i = 0; i < 8; ++i) r[i] = (short)(v[i] ^ (short)0x8000);
  return r;
}

// ---------------- encoder: patch-embed GEMM (fp32, runs once) ----------------
__global__ __launch_bounds__(256) void encoder_kernel(
    const float* __restrict__ x, const float* __restrict__ ew,
    const float* __restrict__ eb, float* __restrict__ zr, float* __restrict__ zi) {
  __shared__ float As[BK][BM];
  __shared__ float Ws[BK][BN];
  const int m0 = blockIdx.x * BM;
  const int o0 = blockIdx.y * BN;
  const int tid = threadIdx.x;
  const int tn = tid & 15, tm = tid >> 4;
  float acc[4][4] = {};
  for (int k0 = 0; k0 < 1024; k0 += BK) {
    for (int s = tid; s < 512; s += 256) {
      {
        int r = s >> 3, kk = (s & 7) << 2;
        int row = m0 + r;
        int frame = row >> 8, pix = row & 255;
        int h = pix >> 4, w = pix & 15;
        int k = k0 + kk;
        int c = k >> 8, rem = k & 255;
        int ph = rem >> 4, pw = rem & 15;
        const float4 v = *(const float4*)(x + (((size_t)(frame * 4 + c) * 256 + h * 16 + ph) * 256 + w * 16 + pw));
        As[kk + 0][r] = v.x; As[kk + 1][r] = v.y; As[kk + 2][r] = v.z; As[kk + 3][r] = v.w;
      }
      {
        int oo = s >> 3, kk = (s & 7) << 2;
        const float4 v = *(const float4*)(ew + (size_t)(o0 + oo) * 1024 + k0 + kk);
        Ws[kk + 0][oo] = v.x; Ws[kk + 1][oo] = v.y; Ws[kk + 2][oo] = v.z; Ws[kk + 3][oo] = v.w;
      }
    }
    __syncthreads();
#pragma unroll
    for (int kk = 0; kk < BK; ++kk) {
      float4 a4 = *(const float4*)&As[kk][tm << 2];
      float4 w4 = *(const float4*)&Ws[kk][tn << 2];
      float a[4] = {a4.x, a4.y, a4.z, a4.w};
      float w[4] = {w4.x, w4.y, w4.z, w4.w};
#pragma unroll
      for (int i = 0; i < 4; ++i)
#pragma unroll
        for (int j = 0; j < 4; ++j) acc[i][j] = fmaf(a[i], w[j], acc[i][j]);
    }
    __syncthreads();
  }
#pragma unroll
  for (int i = 0; i < 4; ++i) {
    int row = m0 + (tm << 2) + i;
#pragma unroll
    for (int j = 0; j < 4; ++j) {
      int o = o0 + (tn << 2) + j;
      float v = acc[i][j] + eb[o];
      if (o < 384) zr[(size_t)row * 384 + o] = v;
      else         zi[(size_t)row * 384 + o - 384] = v;
    }
  }
}

// ---------------- conv weight reorder: cwl[o][c][tap] fp32 -> Btc[o][tap*768+c] bf16 ----------------
__global__ __launch_bounds__(256) void reorder_cw_kernel(
    const float* __restrict__ cwl, u16* __restrict__ Btc) {
  int idx = blockIdx.x * 256 + threadIdx.x;
  if (idx >= 768 * 6912) return;
  int o = idx / 6912, k = idx % 6912;
  int tap = k / 768, c = k % 768;
  Btc[idx] = f2bf(cwl[((size_t)o * 768 + c) * 9 + tap]);
}

// ---------------- dense weight transpose: W[K][N] fp32 -> Wt[N][K] bf16 ----------------
__global__ __launch_bounds__(256) void transpose_bf16_kernel(
    const float* __restrict__ W, u16* __restrict__ Wt, int K, int N) {
  __shared__ float tile[32][33];
  const int k0 = blockIdx.x * 32, n0 = blockIdx.y * 32;
  const int c = threadIdx.x & 31, r8 = threadIdx.x >> 5;
  for (int rr = r8; rr < 32; rr += 8)
    tile[rr][c] = W[(size_t)(k0 + rr) * N + n0 + c];
  __syncthreads();
  for (int rr = r8; rr < 32; rr += 8)
    Wt[(size_t)(n0 + rr) * K + k0 + c] = f2bf(tile[c][rr]);
}

// ---------------- LayerNorm over 768, bf16 output planes ----------------
__global__ __launch_bounds__(256) void ln_bf16_kernel(
    const float* __restrict__ inr, const float* __restrict__ ini,
    const float* __restrict__ g, const float* __restrict__ b,
    u16* __restrict__ outr, u16* __restrict__ outi) {
  const int row = blockIdx.x;
  const int tid = threadIdx.x;
  float v[3];
#pragma unroll
  for (int j = 0; j < 3; ++j) {
    int c = tid + j * 256;
    v[j] = (c < 384) ? inr[(size_t)row * 384 + c] : ini[(size_t)row * 384 + c - 384];
  }
  float s = v[0] + v[1] + v[2];
  float q = v[0] * v[0] + v[1] * v[1] + v[2] * v[2];
#pragma unroll
  for (int off = 32; off > 0; off >>= 1) {
    s += __shfl_down(s, off);
    q += __shfl_down(q, off);
  }
  __shared__ float rs[4], rq[4];
  __shared__ float s_mean, s_inv;
  int wv = tid >> 6;
  if ((tid & 63) == 0) { rs[wv] = s; rq[wv] = q; }
  __syncthreads();
  if (tid == 0) {
    float S = rs[0] + rs[1] + rs[2] + rs[3];
    float Q = rq[0] + rq[1] + rq[2] + rq[3];
    float mean = S * (1.0f / 768.0f);
    float var = Q * (1.0f / 768.0f) - mean * mean;
    s_mean = mean;
    s_inv = rsqrtf(var + 1e-5f);
  }
  __syncthreads();
  float mean = s_mean, inv = s_inv;
#pragma unroll
  for (int j = 0; j < 3; ++j) {
    int c = tid + j * 256;
    float o = (v[j] - mean) * inv * g[c] + b[c];
    if (c < 384) outr[(size_t)row * 384 + c] = f2bf(o);
    else         outi[(size_t)row * 384 + c - 384] = f2bf(o);
  }
}

// ---------------- conv3x3 implicit-GEMM MFMA ----------------
// A: gathered bf16 LN output planes [12288][384]x2, K = tap*768 + c (216 k-steps)
// B: Btc[o][k] bf16. Epilogue: z += v + bias (fp32) and zb = bf16(z)
__global__ __launch_bounds__(256) void conv3x3_mfma_kernel(
    const u16* __restrict__ xnbr, const u16* __restrict__ xnbi,
    const u16* __restrict__ Btc, const float* __restrict__ cbias,
    float* __restrict__ zr, float* __restrict__ zi,
    u16* __restrict__ zbr, u16* __restrict__ zbi) {
  __shared__ u16 As[BM * LDA_S];
  __shared__ u16 Bs[BN * LDA_S];
  const int m0 = blockIdx.x * BM;
  const int o0 = blockIdx.y * BN;
  const int tid = threadIdx.x;
  const int lane = tid & 63, lane15 = lane & 15, quad = lane >> 4;
  const int wv = tid >> 6, wy = wv >> 1, wx = wv & 1;
  const int rr = tid >> 2, kk8 = (tid & 3) * 8;

  // precompute A-gather row geometry
  const int row = m0 + rr;
  const int frame = row >> 8, pix = row & 255;
  const int ph = pix >> 4, pw = pix & 15;

  f32x4 acc[2][2] = {};
  for (int ks = 0; ks < 216; ++ks) {
    const int tap = ks / 24;
    const int c0 = (ks % 24) * 32;
    const int dy = tap / 3 - 1, dx = tap % 3 - 1;
    const u16* plane = (c0 < 384) ? xnbr : xnbi;
    const int cc = (c0 < 384) ? c0 : c0 - 384;
    {
      const int h = ph + dy, w = pw + dx;
      uint4 v = {0u, 0u, 0u, 0u};
      if ((unsigned)h < 16u && (unsigned)w < 16u)
        v = *(const uint4*)(plane + (size_t)(frame * 256 + h * 16 + w) * 384 + cc + kk8);
      *(uint4*)&As[rr * LDA_S + kk8] = v;
      const uint4 w4 = *(const uint4*)(Btc + (size_t)(o0 + rr) * 6912 + (size_t)tap * 768 + c0 + kk8);
      *(uint4*)&Bs[rr * LDA_S + kk8] = w4;
    }
    __syncthreads();
    bf16x8 a0 = *(const bf16x8*)&As[(wy * 32 + lane15) * LDA_S + quad * 8];
    bf16x8 a1 = *(const bf16x8*)&As[(wy * 32 + 16 + lane15) * LDA_S + quad * 8];
    bf16x8 b0 = *(const bf16x8*)&Bs[(wx * 32 + lane15) * LDA_S + quad * 8];
    bf16x8 b1 = *(const bf16x8*)&Bs[(wx * 32 + 16 + lane15) * LDA_S + quad * 8];
    acc[0][0] = __builtin_amdgcn_mfma_f32_16x16x32_bf16(a0, b0, acc[0][0], 0, 0, 0);
    acc[0][1] = __builtin_amdgcn_mfma_f32_16x16x32_bf16(a0, b1, acc[0][1], 0, 0, 0);
    acc[1][0] = __builtin_amdgcn_mfma_f32_16x16x32_bf16(a1, b0, acc[1][0], 0, 0, 0);
    acc[1][1] = __builtin_amdgcn_mfma_f32_16x16x32_bf16(a1, b1, acc[1][1], 0, 0, 0);
    __syncthreads();
  }
#pragma unroll
  for (int i = 0; i < 2; ++i) {
    const int mb = m0 + wy * 32 + i * 16 + quad * 4;
#pragma unroll
    for (int j = 0; j < 2; ++j) {
      const int col = o0 + wx * 32 + j * 16 + lane15;
      const float bias = cbias[col];
#pragma unroll
      for (int r = 0; r < 4; ++r) {
        const int m = mb + r;
        const float v = acc[i][j][r] + bias;
        if (col < 384) {
          size_t idx = (size_t)m * 384 + col;
          float nz = zr[idx] + v;
          zr[idx] = nz; zbr[idx] = f2bf(nz);
        } else {
          size_t idx = (size_t)m * 384 + col - 384;
          float nz = zi[idx] + v;
          zi[idx] = nz; zbi[idx] = f2bf(nz);
        }
      }
    }
  }
}

// ---------------- complex MFMA GEMM: C = A(MxK) * W(KxN), Wt is [N][K] bf16 ----------------
template <bool GELU, bool ACCUM, bool FPOUT, bool BFOUT>
__global__ __launch_bounds__(256) void cgemm_mfma_kernel(
    const u16* __restrict__ Ar, const u16* __restrict__ Ai, int lda,
    const u16* __restrict__ Wtr, const u16* __restrict__ Wti, int ldb,
    float* __restrict__ Cr, float* __restrict__ Ci,
    u16* __restrict__ Cbr, u16* __restrict__ Cbi, int ldc, int K) {
  __shared__ u16 Asr[BM * LDA_S], Asi[BM * LDA_S];
  __shared__ u16 Bsr[BN * LDA_S], Bsi[BN * LDA_S];
  const int m0 = blockIdx.x * BM;
  const int n0 = blockIdx.y * BN;
  const int tid = threadIdx.x;
  const int lane = tid & 63, lane15 = lane & 15, quad = lane >> 4;
  const int wv = tid >> 6, wy = wv >> 1, wx = wv & 1;
  const int rr = tid >> 2, kk8 = (tid & 3) * 8;

  f32x4 accr[2][2] = {}, acci[2][2] = {};
  for (int k0 = 0; k0 < K; k0 += BK) {
    *(uint4*)&Asr[rr * LDA_S + kk8] = *(const uint4*)(Ar + (size_t)(m0 + rr) * lda + k0 + kk8);
    *(uint4*)&Asi[rr * LDA_S + kk8] = *(const uint4*)(Ai + (size_t)(m0 + rr) * lda + k0 + kk8);
    *(uint4*)&Bsr[rr * LDA_S + kk8] = *(const uint4*)(Wtr + (size_t)(n0 + rr) * ldb + k0 + kk8);
    *(uint4*)&Bsi[rr * LDA_S + kk8] = *(const uint4*)(Wti + (size_t)(n0 + rr) * ldb + k0 + kk8);
    __syncthreads();
    bf16x8 ar0 = *(const bf16x8*)&Asr[(wy * 32 + lane15) * LDA_S + quad * 8];
    bf16x8 ar1 = *(const bf16x8*)&Asr[(wy * 32 + 16 + lane15) * LDA_S + quad * 8];
    bf16x8 ai0 = *(const bf16x8*)&Asi[(wy * 32 + lane15) * LDA_S + quad * 8];
    bf16x8 ai1 = *(const bf16x8*)&Asi[(wy * 32 + 16 + lane15) * LDA_S + quad * 8];
    bf16x8 br0 = *(const bf16x8*)&Bsr[(wx * 32 + lane15) * LDA_S + quad * 8];
    bf16x8 br1 = *(const bf16x8*)&Bsr[(wx * 32 + 16 + lane15) * LDA_S + quad * 8];
    bf16x8 bi0 = *(const bf16x8*)&Bsi[(wx * 32 + lane15) * LDA_S + quad * 8];
    bf16x8 bi1 = *(const bf16x8*)&Bsi[(wx * 32 + 16 + lane15) * LDA_S + quad * 8];
    bf16x8 an0 = neg8(ai0), an1 = neg8(ai1);
    // accr += ar*br - ai*bi ; acci += ar*bi + ai*br
    accr[0][0] = __builtin_amdgcn_mfma_f32_16x16x32_bf16(ar0, br0, accr[0][0], 0, 0, 0);
    accr[0][0] = __builtin_amdgcn_mfma_f32_16x16x32_bf16(an0, bi0, accr[0][0], 0, 0, 0);
    accr[0][1] = __builtin_amdgcn_mfma_f32_16x16x32_bf16(ar0, br1, accr[0][1], 0, 0, 0);
    accr[0][1] = __builtin_amdgcn_mfma_f32_16x16x32_bf16(an0, bi1, accr[0][1], 0, 0, 0);
    accr[1][0] = __builtin_amdgcn_mfma_f32_16x16x32_bf16(ar1, br0, accr[1][0], 0, 0, 0);
    accr[1][0] = __builtin_amdgcn_mfma_f32_16x16x32_bf16(an1, bi0, accr[1][0], 0, 0, 0);
    accr[1][1] = __builtin_amdgcn_mfma_f32_16x16x32_bf16(ar1, br1, accr[1][1], 0, 0, 0);
    accr[1][1] = __builtin_amdgcn_mfma_f32_16x16x32_bf16(an1, bi1, accr[1][1], 0, 0, 0);
    acci[0][0] = __builtin_amdgcn_mfma_f32_16x16x32_bf16(ar0, bi0, acci[0][0], 0, 0, 0);
    acci[0][0] = __builtin_amdgcn_mfma_f32_16x16x32_bf16(ai0, br0, acci[0][0], 0, 0, 0);
    acci[0][1] = __builtin_amdgcn_mfma_f32_16x16x32_bf16(ar0, bi1, acci[0][1], 0, 0, 0);
    acci[0][1] = __builtin_amdgcn_mfma_f32_16x16x32_bf16(ai0, br1, acci[0][1], 0, 0, 0);
    acci[1][0] = __builtin_amdgcn_mfma_f32_16x16x32_bf16(ar1, bi0, acci[1][0], 0, 0, 0);
    acci[1][0] = __builtin_amdgcn_mfma_f32_16x16x32_bf16(ai1, br0, acci[1][0], 0, 0, 0);
    acci[1][1] = __builtin_amdgcn_mfma_f32_16x16x32_bf16(ar1, bi1, acci[1][1], 0, 0, 0);
    acci[1][1] = __builtin_amdgcn_mfma_f32_16x16x32_bf16(ai1, br1, acci[1][1], 0, 0, 0);
    __syncthreads();
  }
#pragma unroll
  for (int i = 0; i < 2; ++i) {
    const int mb = m0 + wy * 32 + i * 16 + quad * 4;
#pragma unroll
    for (int j = 0; j < 2; ++j) {
      const int col = n0 + wx * 32 + j * 16 + lane15;
#pragma unroll
      for (int r = 0; r < 4; ++r) {
        const int m = mb + r;
        float vr = accr[i][j][r], vi = acci[i][j][r];
        if (GELU) { vr = gelu_tanh(vr); vi = gelu_tanh(vi); }
        const size_t idx = (size_t)m * ldc + col;
        if (ACCUM) { vr += Cr[idx]; vi += Ci[idx]; }
        if (FPOUT) { Cr[idx] = vr; Ci[idx] = vi; }
        if (BFOUT) { Cbr[idx] = f2bf(vr); Cbi[idx] = f2bf(vi); }
      }
    }
  }
}

// ---------------- small fp32 complex GEMM (M=48: source term) ----------------
__global__ __launch_bounds__(256) void cgemm_small_kernel(
    const float* __restrict__ Ar, const float* __restrict__ Ai, int lda,
    const float* __restrict__ Wr, const float* __restrict__ Wi, int ldw,
    float* __restrict__ Cr, float* __restrict__ Ci, int ldc, int M, int K) {
  __shared__ float Asr[BK][BM], Asi[BK][BM];
  __shared__ float Wsr[BK][BN], Wsi[BK][BN];
  const int m0 = blockIdx.x * BM;
  const int n0 = blockIdx.y * BN;
  const int tid = threadIdx.x;
  const int tn = tid & 15, tm = tid >> 4;
  float accr[4][4] = {}, acci[4][4] = {};
  for (int k0 = 0; k0 < K; k0 += BK) {
    for (int s = tid; s < 512; s += 256) {
      {
        int r = s >> 3, kk = (s & 7) << 2;
        int row = m0 + r;
        float4 vr = {0.f, 0.f, 0.f, 0.f}, vi = {0.f, 0.f, 0.f, 0.f};
        if (row < M) {
          vr = *(const float4*)(Ar + (size_t)row * lda + k0 + kk);
          vi = *(const float4*)(Ai + (size_t)row * lda + k0 + kk);
        }
        Asr[kk + 0][r] = vr.x; Asr[kk + 1][r] = vr.y; Asr[kk + 2][r] = vr.z; Asr[kk + 3][r] = vr.w;
        Asi[kk + 0][r] = vi.x; Asi[kk + 1][r] = vi.y; Asi[kk + 2][r] = vi.z; Asi[kk + 3][r] = vi.w;
      }
      {
        int wr_ = s >> 4, wc = (s & 15) << 2;
        *(float4*)&Wsr[wr_][wc] = *(const float4*)(Wr + (size_t)(k0 + wr_) * ldw + n0 + wc);
        *(float4*)&Wsi[wr_][wc] = *(const float4*)(Wi + (size_t)(k0 + wr_) * ldw + n0 + wc);
      }
    }
    __syncthreads();
#pragma unroll
    for (int kk = 0; kk < BK; ++kk) {
      float4 ar4 = *(const float4*)&Asr[kk][tm << 2];
      float4 ai4 = *(const float4*)&Asi[kk][tm << 2];
      float4 wr4 = *(const float4*)&Wsr[kk][tn << 2];
      float4 wi4 = *(const float4*)&Wsi[kk][tn << 2];
      float ar[4] = {ar4.x, ar4.y, ar4.z, ar4.w};
      float ai[4] = {ai4.x, ai4.y, ai4.z, ai4.w};
      float wr[4] = {wr4.x, wr4.y, wr4.z, wr4.w};
      float wi[4] = {wi4.x, wi4.y, wi4.z, wi4.w};
#pragma unroll
      for (int i = 0; i < 4; ++i)
#pragma unroll
        for (int j = 0; j < 4; ++j) {
          accr[i][j] = fmaf(ar[i], wr[j], accr[i][j]);
          accr[i][j] = fmaf(-ai[i], wi[j], accr[i][j]);
          acci[i][j] = fmaf(ar[i], wi[j], acci[i][j]);
          acci[i][j] = fmaf(ai[i], wr[j], acci[i][j]);
        }
    }
    __syncthreads();
  }
#pragma unroll
  for (int i = 0; i < 4; ++i) {
    int row = m0 + (tm << 2) + i;
    if (row >= M) continue;
#pragma unroll
    for (int j = 0; j < 4; ++j) {
      int col = n0 + (tn << 2) + j;
      size_t idx = (size_t)row * ldc + col;
      Cr[idx] = accr[i][j]; Ci[idx] = acci[i][j];
    }
  }
}

// ---------------- mean over 256 pixels ----------------
__global__ __launch_bounds__(384) void mean_kernel(
    const float* __restrict__ eigr, const float* __restrict__ eigi,
    float* __restrict__ mr, float* __restrict__ mi) {
  const int frame = blockIdx.x;
  const int d = threadIdx.x;
  const float* in = blockIdx.y ? eigi : eigr;
  float* out = blockIdx.y ? mi : mr;
  const float* p = in + (size_t)frame * 256 * 384 + d;
  float s = 0.f;
#pragma unroll 4
  for (int px = 0; px < 256; ++px) s += p[(size_t)px * 384];
  out[frame * 384 + d] = s * (1.0f / 256.0f);
}

// ---------------- flux scan + operator precompute ----------------
__global__ __launch_bounds__(384) void flux_kernel(
    const float* __restrict__ dt, const float* __restrict__ lamf,
    const float* __restrict__ nu, const float* __restrict__ omega,
    const float* __restrict__ mr, const float* __restrict__ mi,
    float* __restrict__ fluxr, float* __restrict__ fluxi,
    float* __restrict__ opdr, float* __restrict__ opdi,
    float* __restrict__ opfr, float* __restrict__ opfi) {
  const int b = blockIdx.x;
  const int d = threadIdx.x;
  const float sp = softplus_f(lamf[d]);
  float lre = -softplus_f(nu[d]);
  lre = fmaxf(lre, -5.0f);
  const float lim = omega[d];
  const float den = lre * lre + lim * lim;
  float fr = 0.f, fi = 0.f;
  for (int t = 0; t < 12; ++t) {
    const float dtv = dt[b * 12 + t];
    const int idx = (b * 12 + t) * 384 + d;
    const float A = expf(-sp * dtv);
    fr = A * fr + mr[idx] * dtv;
    fi = A * fi + mi[idx] * dtv;
    fluxr[idx] = fr; fluxi[idx] = fi;
    const float ed = expf(lre * dtv);
    const float odr = ed * cosf(lim * dtv);
    const float odi = ed * sinf(lim * dtv);
    opdr[idx] = odr; opdi[idx] = odi;
    const float nr_ = odr - 1.0f, ni_ = odi;
    opfr[idx] = (nr_ * lre + ni_ * lim) / den;
    opfi[idx] = (ni_ * lre - nr_ * lim) / den;
  }
}

// ---------------- forcing + u_t (in-place on eig, fp32) ----------------
__global__ __launch_bounds__(256) void forcing_kernel(
    float* __restrict__ eigr, float* __restrict__ eigi,
    const float* __restrict__ fluxr,
    const float* __restrict__ srcr, const float* __restrict__ srci,
    const float* __restrict__ Wg,
    const float* __restrict__ opfr, const float* __restrict__ opfi, int total) {
  const int g = blockIdx.x * 256 + threadIdx.x;
  if (g >= total) return;
  const int d = g % 384;
  const int fp = g / 384;
  const int fidx = (fp >> 8) * 384 + d;
  const float gate = 1.0f / (1.0f + expf(-fluxr[fidx] * Wg[d]));
  const float er = eigr[g], ei = eigi[g];
  const float fr = er * gate + srcr[fidx] * (1.0f - gate);
  const float fi = ei * gate + srci[fidx] * (1.0f - gate);
  const float pr = opfr[fidx], pi = opfi[fidx];
  eigr[g] = fr * pr - fi * pi;
  eigi[g] = fr * pi + fi * pr;
}

// ---------------- u_out pscan over T: reads eig fp32, writes bf16 u ----------------
__global__ __launch_bounds__(256) void pscan_u_kernel(
    const float* __restrict__ eigr, const float* __restrict__ eigi,
    const float* __restrict__ opdr, const float* __restrict__ opdi,
    u16* __restrict__ ubr, u16* __restrict__ ubi) {
  const int g = blockIdx.x * 256 + threadIdx.x;
  if (g >= 4 * 256 * 384) return;
  const int d = g % 384;
  const int pix = (g / 384) & 255;
  const int b = g / (384 * 256);
  float ur = 0.f, ui = 0.f;
  for (int t = 0; t < 12; ++t) {
    const int frame = b * 12 + t;
    const size_t idx = ((size_t)frame * 256 + pix) * 384 + d;
    const int fidx = frame * 384 + d;
    const float ar = opdr[fidx], ai = opdi[fidx];
    const float nr = ar * ur - ai * ui + eigr[idx];
    const float ni = ar * ui + ai * ur + eigi[idx];
    ubr[idx] = f2bf(nr); ubi[idx] = f2bf(ni);
    ur = nr; ui = ni;
  }
}

// ---------------- z += df ----------------
__global__ __launch_bounds__(256) void add_df_kernel(
    float* __restrict__ zr, float* __restrict__ zi,
    const float* __restrict__ dfr, const float* __restrict__ dfi, int n) {
  const int g = blockIdx.x * 256 + threadIdx.x;
  if (g < n) { zr[g] += dfr[g]; zi[g] += dfi[g]; }
}

// ---------------- decoder GEMM + patch scatter (fp32, runs once) ----------------
__global__ __launch_bounds__(256) void decoder_kernel(
    const float* __restrict__ zr, const float* __restrict__ zi,
    const float* __restrict__ dw, const float* __restrict__ db,
    float* __restrict__ out) {
  __shared__ float As[BK][BM];
  __shared__ float Ws[BK][BN];
  const int m0 = blockIdx.x * BM;
  const int o0 = blockIdx.y * BN;
  const int tid = threadIdx.x;
  const int tn = tid & 15, tm = tid >> 4;
  float acc[4][4] = {};
  for (int k0 = 0; k0 < 768; k0 += BK) {
    for (int s = tid; s < 512; s += 256) {
      {
        int r = s >> 3, kk = (s & 7) << 2;
        int row = m0 + r;
        int k = k0 + kk;
        const float* pl = (k < 384) ? zr : zi;
        int kc = (k < 384) ? k : k - 384;
        const float4 v = *(const float4*)(pl + (size_t)row * 384 + kc);
        As[kk + 0][r] = v.x; As[kk + 1][r] = v.y; As[kk + 2][r] = v.z; As[kk + 3][r] = v.w;
      }
      {
        int oo = s >> 3, kk = (s & 7) << 2;
        const float4 v = *(const float4*)(dw + (size_t)(o0 + oo) * 768 + k0 + kk);
        Ws[kk + 0][oo] = v.x; Ws[kk + 1][oo] = v.y; Ws[kk + 2][oo] = v.z; Ws[kk + 3][oo] = v.w;
      }
    }
    __syncthreads();
#pragma unroll
    for (int kk = 0; kk < BK; ++kk) {
      float4 a4 = *(const float4*)&As[kk][tm << 2];
      float4 w4 = *(const float4*)&Ws[kk][tn << 2];
      float a[4] = {a4.x, a4.y, a4.z, a4.w};
      float w[4] = {w4.x, w4.y, w4.z, w4.w};
#pragma unroll
      for (int i = 0; i < 4; ++i)
#pragma unroll
        for (int j = 0; j < 4; ++j) acc[i][j] = fmaf(a[i], w[j], acc[i][j]);
    }
    __syncthreads();
  }
#pragma unroll
  for (int i = 0; i < 4; ++i) {
    int row = m0 + (tm << 2) + i;
    int frame = row >> 8, pix = row & 255;
    int hp = pix >> 4, wp = pix & 15;
#pragma unroll
    for (int j = 0; j < 4; ++j) {
      int o = o0 + (tn << 2) + j;
      int co = o >> 8, p1 = (o >> 4) & 15, p2 = o & 15;
      out[(((size_t)frame * 4 + co) * 256 + hp * 16 + p1) * 256 + wp * 16 + p2] = acc[i][j] + db[o];
    }
  }
}

extern "C" void kernel_launch(void* const* d_in, const int* in_sizes, int n_in,
                              void* d_out, int out_size, void* d_ws, size_t ws_size,
                              hipStream_t stream) {
  const float* x        = (const float*)d_in[0];
  const float* dt       = (const float*)d_in[1];
  const float* enc_w    = (const float*)d_in[2];
  const float* enc_b    = (const float*)d_in[3];
  const float* ns_g     = (const float*)d_in[4];
  const float* ns_b     = (const float*)d_in[5];
  const float* cw       = (const float*)d_in[6];
  const float* cb       = (const float*)d_in[7];
  const float* nt_g     = (const float*)d_in[8];
  const float* nt_b     = (const float*)d_in[9];
  const float* E_re     = (const float*)d_in[10];
  const float* E_im     = (const float*)d_in[11];
  const float* Ei_re    = (const float*)d_in[12];
  const float* Ei_im    = (const float*)d_in[13];
  const float* lam_flux = (const float*)d_in[14];
  const float* Ws_re    = (const float*)d_in[15];
  const float* Ws_im    = (const float*)d_in[16];
  const float* Wg       = (const float*)d_in[17];
  const float* nu       = (const float*)d_in[18];
  const float* omega    = (const float*)d_in[19];
  const float* w1_re    = (const float*)d_in[20];
  const float* w1_im    = (const float*)d_in[21];
  const float* w2_re    = (const float*)d_in[22];
  const float* w2_im    = (const float*)d_in[23];
  const float* dec_w    = (const float*)d_in[24];
  const float* dec_b    = (const float*)d_in[25];
  float* out = (float*)d_out;

  const size_t NP = 48ull * 256 * 384;      // 4,718,592 per plane
  const size_t SM = 48ull * 384;

  // layout: fp32 blocks, then bf16 blocks, then small fp32
  float* ws   = (float*)d_ws;
  float* zr   = ws;             float* zi   = zr + NP;
  float* eigr = zi + NP;        float* eigi = eigr + NP;
  float* dfr  = eigi + NP;      float* dfi  = dfr + NP;
  u16* ub     = (u16*)(dfi + NP);
  u16* xnbr = ub;               u16* xnbi = xnbr + NP;   // LN outputs; aliased by pscan ub
  u16* zbr  = xnbi + NP;        u16* zbi  = zbr + NP;
  u16* Btc  = zbi + NP;                                   // 768*6912
  u16* Etr  = Btc + 768 * 6912; u16* Eti  = Etr + 147456;
  u16* Eitr = Eti + 147456;     u16* Eiti = Eitr + 147456;
  u16* W1tr = Eiti + 147456;    u16* W1ti = W1tr + 589824;
  u16* W2tr = W1ti + 589824;    u16* W2ti = W2tr + 589824;
  float* sm = (float*)(W2ti + 589824);
  float* mr    = sm;            float* mi    = mr + SM;
  float* fluxr = mi + SM;       float* fluxi = fluxr + SM;
  float* opdr  = fluxi + SM;    float* opdi  = opdr + SM;
  float* opfr  = opdi + SM;     float* opfi  = opfr + SM;
  float* srcr  = opfi + SM;     float* srci  = srcr + SM;

  const size_t need = ((char*)(srci + SM)) - ((char*)d_ws);
  if (ws_size < need) return;

  // h1 (bf16) overlays eig (dead between pscan and next-layer E-GEMM)
  u16* h1br = (u16*)eigr;  // 12288*768 bf16 fits in NP floats
  u16* h1bi = (u16*)eigi;

  encoder_kernel<<<dim3(192, 12), 256, 0, stream>>>(x, enc_w, enc_b, zr, zi);

  for (int l = 0; l < 4; ++l) {
    const size_t DD = 384ull * 384, DF = 384ull * 1536;
    reorder_cw_kernel<<<(768 * 6912 + 255) / 256, 256, 0, stream>>>(cw + (size_t)l * 768 * 768 * 9, Btc);
    transpose_bf16_kernel<<<dim3(12, 12), 256, 0, stream>>>(E_re + l * DD, Etr, 384, 384);
    transpose_bf16_kernel<<<dim3(12, 12), 256, 0, stream>>>(E_im + l * DD, Eti, 384, 384);
    transpose_bf16_kernel<<<dim3(12, 12), 256, 0, stream>>>(Ei_re + l * DD, Eitr, 384, 384);
    transpose_bf16_kernel<<<dim3(12, 12), 256, 0, stream>>>(Ei_im + l * DD, Eiti, 384, 384);
    transpose_bf16_kernel<<<dim3(12, 48), 256, 0, stream>>>(w1_re + l * DF, W1tr, 384, 1536);
    transpose_bf16_kernel<<<dim3(12, 48), 256, 0, stream>>>(w1_im + l * DF, W1ti, 384, 1536);
    transpose_bf16_kernel<<<dim3(48, 12), 256, 0, stream>>>(w2_re + l * DF, W2tr, 1536, 384);
    transpose_bf16_kernel<<<dim3(48, 12), 256, 0, stream>>>(w2_im + l * DF, W2ti, 1536, 384);

    ln_bf16_kernel<<<12288, 256, 0, stream>>>(zr, zi, ns_g + l * 768, ns_b + l * 768, xnbr, xnbi);
    conv3x3_mfma_kernel<<<dim3(192, 12), 256, 0, stream>>>(xnbr, xnbi, Btc, cb + l * 768, zr, zi, zbr, zbi);
    cgemm_mfma_kernel<false, false, true, false><<<dim3(192, 6), 256, 0, stream>>>(
        zbr, zbi, 384, Etr, Eti, 384, eigr, eigi, nullptr, nullptr, 384, 384);
    mean_kernel<<<dim3(48, 2), 384, 0, stream>>>(eigr, eigi, mr, mi);
    flux_kernel<<<4, 384, 0, stream>>>(dt, lam_flux + l * 384, nu + l * 384, omega + l * 384,
                                       mr, mi, fluxr, fluxi, opdr, opdi, opfr, opfi);
    cgemm_small_kernel<<<dim3(1, 6), 256, 0, stream>>>(
        fluxr, fluxi, 384, Ws_re + l * DD, Ws_im + l * DD, 384, srcr, srci, 384, 48, 384);
    forcing_kernel<<<(int)((NP + 255) / 256), 256, 0, stream>>>(
        eigr, eigi, fluxr, srcr, srci, Wg + l * 384, opfr, opfi, (int)NP);
    pscan_u_kernel<<<1536, 256, 0, stream>>>(eigr, eigi, opdr, opdi, xnbr, xnbi);  // ub = xnb alias
    cgemm_mfma_kernel<false, false, true, false><<<dim3(192, 6), 256, 0, stream>>>(
        xnbr, xnbi, 384, Eitr, Eiti, 384, dfr, dfi, nullptr, nullptr, 384, 384);
    ln_bf16_kernel<<<12288, 256, 0, stream>>>(dfr, dfi, nt_g + l * 768, nt_b + l * 768, xnbr, xnbi);
    add_df_kernel<<<(int)((NP + 255) / 256), 256, 0, stream>>>(zr, zi, dfr, dfi, (int)NP);
    for (int ch = 0; ch < 2; ++ch) {
      // W1 chunk: N = 768 cols of DFF; h1 = cgelu(xn * W1) in bf16
      cgemm_mfma_kernel<true, false, false, true><<<dim3(192, 12), 256, 0, stream>>>(
          xnbr, xnbi, 384, W1tr + (size_t)ch * 768 * 384, W1ti + (size_t)ch * 768 * 384, 384,
          nullptr, nullptr, h1br, h1bi, 768, 384);
      // W2 chunk: K = 768 rows of DFF; z += h1 * W2
      cgemm_mfma_kernel<false, true, true, false><<<dim3(192, 6), 256, 0, stream>>>(
          h1br, h1bi, 768, W2tr + (size_t)ch * 768, W2ti + (size_t)ch * 768, 1536,
          zr, zi, nullptr, nullptr, 384, 768);
    }
  }

  decoder_kernel<<<dim3(192, 16), 256, 0, stream>>>(zr, zi, dec_w, dec_b, out);
}

// Round 3
// 2954.191 us; speedup vs baseline: 5.6806x; 1.3793x over previous
//
#include <hip/hip_runtime.h>
#include <cstddef>
#include <cstdint>

typedef unsigned short u16;
typedef short bf16x8 __attribute__((ext_vector_type(8)));
typedef float f32x4 __attribute__((ext_vector_type(4)));

__device__ __forceinline__ float gelu_tanh(float x) {
  float x3 = x * x * x;
  float t = tanhf(0.7978845608028654f * (x + 0.044715f * x3));
  return 0.5f * x * (1.0f + t);
}
__device__ __forceinline__ float softplus_f(float x) {
  return (x > 20.0f) ? x : log1pf(expf(x));
}
__device__ __forceinline__ u16 f2bf(float f) {
  uint32_t u = __float_as_uint(f);
  uint32_t r = (u + 0x7fffu + ((u >> 16) & 1u)) >> 16;
  return (u16)r;
}

// async global->LDS, 16B per lane; LDS dest = wave-uniform base + lane*16
__device__ __forceinline__ void gload16(const u16* g, u16* l) {
  __builtin_amdgcn_global_load_lds(
      (const __attribute__((address_space(1))) void*)g,
      (__attribute__((address_space(3))) void*)l, 16, 0, 0);
}

// ==================== unified 128x128 MFMA GEMM ====================
// A [M][K] bf16 row-major; Bt [N][K] bf16; M = grid.x*128, N = grid.y*128.
// MODE 0: Cf[row*ldc+col] = v
// MODE 1: Cb[row*ldc+col] = bf16(gelu(v))
// MODE 2: Cf[row*ldc+col] += v
// MODE 3: decoder scatter: out[(frame,co,hp*16+p1,wp*16+p2)] = v + bias[col]
template <int MODE>
__global__ __launch_bounds__(256) void gemm128_kernel(
    const u16* __restrict__ A, const u16* __restrict__ Bt, int K, int ldc,
    float* __restrict__ Cf, u16* __restrict__ Cb, const float* __restrict__ bias) {
  __shared__ u16 As[128 * 32];
  __shared__ u16 Bs[128 * 32];
  const int m0 = blockIdx.x * 128, n0 = blockIdx.y * 128;
  const int tid = threadIdx.x;
  const int lane = tid & 63, w = tid >> 6;
  const int lane15 = lane & 15, quad = lane >> 4;
  const int r0 = lane >> 2, e0 = (lane & 3) * 8;

  const u16* ag0 = A + (size_t)(m0 + w * 32 + r0) * K + e0;
  const u16* ag1 = A + (size_t)(m0 + w * 32 + 16 + r0) * K + e0;
  const u16* bg0 = Bt + (size_t)(n0 + w * 32 + r0) * K + e0;
  const u16* bg1 = Bt + (size_t)(n0 + w * 32 + 16 + r0) * K + e0;
  u16* As0 = As + w * 1024; u16* As1 = As0 + 512;
  u16* Bs0 = Bs + w * 1024; u16* Bs1 = Bs0 + 512;

  f32x4 acc[4][4] = {};
  const int wy = w >> 1, wx = w & 1;
  const int ar_base = (wy * 64 + lane15) * 32 + quad * 8;
  const int br_base = (wx * 64 + lane15) * 32 + quad * 8;

  for (int k0 = 0; k0 < K; k0 += 32) {
    gload16(ag0 + k0, As0);
    gload16(ag1 + k0, As1);
    gload16(bg0 + k0, Bs0);
    gload16(bg1 + k0, Bs1);
    __syncthreads();
    bf16x8 af[4], bf[4];
#pragma unroll
    for (int i = 0; i < 4; ++i) af[i] = *(const bf16x8*)&As[ar_base + i * 16 * 32];
#pragma unroll
    for (int j = 0; j < 4; ++j) bf[j] = *(const bf16x8*)&Bs[br_base + j * 16 * 32];
#pragma unroll
    for (int i = 0; i < 4; ++i)
#pragma unroll
      for (int j = 0; j < 4; ++j)
        acc[i][j] = __builtin_amdgcn_mfma_f32_16x16x32_bf16(af[i], bf[j], acc[i][j], 0, 0, 0);
    __syncthreads();
  }

  const int mw = m0 + wy * 64, nw = n0 + wx * 64;
#pragma unroll
  for (int i = 0; i < 4; ++i) {
#pragma unroll
    for (int j = 0; j < 4; ++j) {
      const int col = nw + j * 16 + lane15;
#pragma unroll
      for (int r = 0; r < 4; ++r) {
        const int row = mw + i * 16 + quad * 4 + r;
        const float v = acc[i][j][r];
        if (MODE == 0) {
          Cf[(size_t)row * ldc + col] = v;
        } else if (MODE == 1) {
          Cb[(size_t)row * ldc + col] = f2bf(gelu_tanh(v));
        } else if (MODE == 2) {
          Cf[(size_t)row * ldc + col] += v;
        } else if (MODE == 3) {
          const int frame = row >> 8, pix = row & 255;
          const int hp = pix >> 4, wp = pix & 15;
          const int co = col >> 8, p1 = (col >> 4) & 15, p2 = col & 15;
          Cf[(((size_t)frame * 4 + co) * 256 + hp * 16 + p1) * 256 + wp * 16 + p2] = v + bias[col];
        }
      }
    }
  }
}

// ==================== conv3x3 implicit-GEMM (128x128 MFMA) ====================
// A gathered from halo-padded xnbp [48][18*18][768] bf16; B = Btc [768][6912] bf16.
// Epilogue: z += v + bias; zb = bf16(z).
__global__ __launch_bounds__(256) void conv_mfma128_kernel(
    const u16* __restrict__ xnp, const u16* __restrict__ Btc,
    const float* __restrict__ cbias,
    float* __restrict__ z, u16* __restrict__ zb) {
  __shared__ u16 As[128 * 32];
  __shared__ u16 Bs[128 * 32];
  const int m0 = blockIdx.x * 128, n0 = blockIdx.y * 128;
  const int tid = threadIdx.x;
  const int lane = tid & 63, w = tid >> 6;
  const int lane15 = lane & 15, quad = lane >> 4;
  const int r0 = lane >> 2, e0 = (lane & 3) * 8;

  const int rowA0 = m0 + w * 32 + r0, rowA1 = rowA0 + 16;
  const long long cen0 = ((long long)(rowA0 >> 8) * 324 + ((((rowA0 & 255) >> 4) + 1) * 18) + (rowA0 & 15) + 1) * 768 + e0;
  const long long cen1 = ((long long)(rowA1 >> 8) * 324 + ((((rowA1 & 255) >> 4) + 1) * 18) + (rowA1 & 15) + 1) * 768 + e0;
  const u16* bg0 = Btc + (size_t)(n0 + w * 32 + r0) * 6912 + e0;
  const u16* bg1 = bg0 + (size_t)16 * 6912;
  u16* As0 = As + w * 1024; u16* As1 = As0 + 512;
  u16* Bs0 = Bs + w * 1024; u16* Bs1 = Bs0 + 512;

  f32x4 acc[4][4] = {};
  const int wy = w >> 1, wx = w & 1;
  const int ar_base = (wy * 64 + lane15) * 32 + quad * 8;
  const int br_base = (wx * 64 + lane15) * 32 + quad * 8;

  for (int tap = 0; tap < 9; ++tap) {
    const int doff = ((tap / 3 - 1) * 18 + (tap % 3 - 1)) * 768;
    const u16* a0 = xnp + cen0 + doff;
    const u16* a1 = xnp + cen1 + doff;
    const u16* b0 = bg0 + tap * 768;
    const u16* b1 = bg1 + tap * 768;
    for (int kc = 0; kc < 768; kc += 32) {
      gload16(a0 + kc, As0);
      gload16(a1 + kc, As1);
      gload16(b0 + kc, Bs0);
      gload16(b1 + kc, Bs1);
      __syncthreads();
      bf16x8 af[4], bf[4];
#pragma unroll
      for (int i = 0; i < 4; ++i) af[i] = *(const bf16x8*)&As[ar_base + i * 16 * 32];
#pragma unroll
      for (int j = 0; j < 4; ++j) bf[j] = *(const bf16x8*)&Bs[br_base + j * 16 * 32];
#pragma unroll
      for (int i = 0; i < 4; ++i)
#pragma unroll
        for (int j = 0; j < 4; ++j)
          acc[i][j] = __builtin_amdgcn_mfma_f32_16x16x32_bf16(af[i], bf[j], acc[i][j], 0, 0, 0);
      __syncthreads();
    }
  }

  const int mw = m0 + wy * 64, nw = n0 + wx * 64;
#pragma unroll
  for (int i = 0; i < 4; ++i) {
#pragma unroll
    for (int j = 0; j < 4; ++j) {
      const int col = nw + j * 16 + lane15;
      const float bv = cbias[col];
#pragma unroll
      for (int r = 0; r < 4; ++r) {
        const int row = mw + i * 16 + quad * 4 + r;
        const size_t idx = (size_t)row * 768 + col;
        const float nz = z[idx] + acc[i][j][r] + bv;
        z[idx] = nz;
        zb[idx] = f2bf(nz);
      }
    }
  }
}

// ==================== encoder: patch-embed MFMA (manual fp32->bf16 staging) ====================
__global__ __launch_bounds__(256) void encoder_mfma_kernel(
    const float* __restrict__ x, const float* __restrict__ ew,
    const float* __restrict__ eb, float* __restrict__ z) {
  __shared__ u16 As[128 * 32];
  __shared__ u16 Bs[128 * 32];
  const int m0 = blockIdx.x * 128, n0 = blockIdx.y * 128;
  const int tid = threadIdx.x;
  const int lane = tid & 63, w = tid >> 6;
  const int lane15 = lane & 15, quad = lane >> 4;
  const int srow = tid >> 1, half = tid & 1;
  const int arow = m0 + srow;
  const int frame = arow >> 8, pix = arow & 255, hh = pix >> 4, ww = pix & 15;

  f32x4 acc[4][4] = {};
  const int wy = w >> 1, wx = w & 1;
  const int ar_base = (wy * 64 + lane15) * 32 + quad * 8;
  const int br_base = (wx * 64 + lane15) * 32 + quad * 8;

  for (int k0 = 0; k0 < 1024; k0 += 32) {
    const int gk = k0 + half * 16;
    const int c = gk >> 8, ph = (gk >> 4) & 15;
    const float* ax = x + (((size_t)(frame * 4 + c) * 256 + hh * 16 + ph) * 256 + ww * 16);
    const float* bx = ew + (size_t)(n0 + srow) * 1024 + gk;
    u16 ta[16], tb[16];
#pragma unroll
    for (int j = 0; j < 4; ++j) {
      const float4 va = *(const float4*)(ax + j * 4);
      const float4 vb = *(const float4*)(bx + j * 4);
      ta[j * 4 + 0] = f2bf(va.x); ta[j * 4 + 1] = f2bf(va.y);
      ta[j * 4 + 2] = f2bf(va.z); ta[j * 4 + 3] = f2bf(va.w);
      tb[j * 4 + 0] = f2bf(vb.x); tb[j * 4 + 1] = f2bf(vb.y);
      tb[j * 4 + 2] = f2bf(vb.z); tb[j * 4 + 3] = f2bf(vb.w);
    }
    __syncthreads();
    *(uint4*)&As[srow * 32 + half * 16] = *(uint4*)ta;
    *(uint4*)&As[srow * 32 + half * 16 + 8] = *(uint4*)(ta + 8);
    *(uint4*)&Bs[srow * 32 + half * 16] = *(uint4*)tb;
    *(uint4*)&Bs[srow * 32 + half * 16 + 8] = *(uint4*)(tb + 8);
    __syncthreads();
    bf16x8 af[4], bfv[4];
#pragma unroll
    for (int i = 0; i < 4; ++i) af[i] = *(const bf16x8*)&As[ar_base + i * 16 * 32];
#pragma unroll
    for (int j = 0; j < 4; ++j) bfv[j] = *(const bf16x8*)&Bs[br_base + j * 16 * 32];
#pragma unroll
    for (int i = 0; i < 4; ++i)
#pragma unroll
      for (int j = 0; j < 4; ++j)
        acc[i][j] = __builtin_amdgcn_mfma_f32_16x16x32_bf16(af[i], bfv[j], acc[i][j], 0, 0, 0);
  }

  const int mw = m0 + wy * 64, nw = n0 + wx * 64;
#pragma unroll
  for (int i = 0; i < 4; ++i)
#pragma unroll
    for (int j = 0; j < 4; ++j) {
      const int col = nw + j * 16 + lane15;
      const float bv = eb[col];
#pragma unroll
      for (int r = 0; r < 4; ++r) {
        const int row = mw + i * 16 + quad * 4 + r;
        z[(size_t)row * 768 + col] = acc[i][j][r] + bv;
      }
    }
}

// ==================== weight prep ====================
// expand complex W (Kc x Nc, re/im fp32, row stride ldw) to real Wt [2Nc][2Kc] bf16:
// Wt[n'][k']: n'<Nc,k'<Kc -> re[k][n]; n'<Nc,k'>=Kc -> -im[k-Kc][n];
//             n'>=Nc,k'<Kc -> im[k][n-Nc]; else re[k-Kc][n-Nc]
__global__ __launch_bounds__(256) void expand_kernel(
    const float* __restrict__ Wre, const float* __restrict__ Wim,
    int ldw, int Kc, int Nc, u16* __restrict__ Wt) {
  __shared__ float tile[32][33];
  const int k0 = blockIdx.x * 32, n0 = blockIdx.y * 32;
  const bool khi = k0 >= Kc, nhi = n0 >= Nc;
  const float* src = (khi != nhi) ? Wim : Wre;
  const float sgn = (!nhi && khi) ? -1.0f : 1.0f;
  const int sk = k0 - (khi ? Kc : 0), sn = n0 - (nhi ? Nc : 0);
  const int c = threadIdx.x & 31, r8 = threadIdx.x >> 5;
  for (int r = r8; r < 32; r += 8)
    tile[r][c] = src[(size_t)(sk + r) * ldw + sn + c];
  __syncthreads();
  const int twoK = 2 * Kc;
  for (int r = r8; r < 32; r += 8)
    Wt[(size_t)(n0 + r) * twoK + k0 + c] = f2bf(sgn * tile[c][r]);
}

// conv weight reorder: cwl[o][c][tap] fp32 -> Btc[o][tap*768+c] bf16 (LDS-staged, coalesced)
__global__ __launch_bounds__(256) void reorder_cw_kernel(
    const float* __restrict__ cwl, u16* __restrict__ Btc) {
  __shared__ float buf[6912];
  const int o = blockIdx.x;
  const float* src = cwl + (size_t)o * 6912;
  for (int i = threadIdx.x; i < 6912; i += 256) buf[i] = src[i];
  __syncthreads();
  u16* dst = Btc + (size_t)o * 6912;
  for (int i = threadIdx.x; i < 6912; i += 256) {
    const int tap = i / 768, cc = i - tap * 768;
    dst[i] = f2bf(buf[cc * 9 + tap]);
  }
}

__global__ __launch_bounds__(256) void cast_bf16_kernel(
    const float* __restrict__ in, u16* __restrict__ out, int n) {
  const int g = blockIdx.x * 256 + threadIdx.x;
  if (g < n) out[g] = f2bf(in[g]);
}

// ==================== LayerNorm (contiguous 768) ====================
template <bool HALO>
__global__ __launch_bounds__(192) void ln_kernel(
    const float* __restrict__ in, const float* __restrict__ g,
    const float* __restrict__ b, u16* __restrict__ out) {
  const int row = blockIdx.x, tid = threadIdx.x;
  const float4 v = *(const float4*)(in + (size_t)row * 768 + tid * 4);
  float s = v.x + v.y + v.z + v.w;
  float q = v.x * v.x + v.y * v.y + v.z * v.z + v.w * v.w;
#pragma unroll
  for (int off = 32; off > 0; off >>= 1) {
    s += __shfl_down(s, off);
    q += __shfl_down(q, off);
  }
  __shared__ float rs[3], rq[3];
  if ((tid & 63) == 0) { rs[tid >> 6] = s; rq[tid >> 6] = q; }
  __syncthreads();
  const float S = rs[0] + rs[1] + rs[2], Q = rq[0] + rq[1] + rq[2];
  const float mean = S * (1.0f / 768.0f);
  const float inv = rsqrtf(Q * (1.0f / 768.0f) - mean * mean + 1e-5f);
  const float4 gv = *(const float4*)(g + tid * 4);
  const float4 bv = *(const float4*)(b + tid * 4);
  u16 p[4];
  p[0] = f2bf((v.x - mean) * inv * gv.x + bv.x);
  p[1] = f2bf((v.y - mean) * inv * gv.y + bv.y);
  p[2] = f2bf((v.z - mean) * inv * gv.z + bv.z);
  p[3] = f2bf((v.w - mean) * inv * gv.w + bv.w);
  size_t base;
  if (HALO) {
    const int f = row >> 8, pp = row & 255, h = pp >> 4, ww = pp & 15;
    base = ((size_t)f * 324 + (h + 1) * 18 + ww + 1) * 768;
  } else {
    base = (size_t)row * 768;
  }
  *(uint2*)(out + base + tid * 4) = *(uint2*)p;
}

// ==================== mean over 256 pixels (combined layout) ====================
__global__ __launch_bounds__(768) void mean_kernel(
    const float* __restrict__ eig, float* __restrict__ mr, float* __restrict__ mi) {
  const int f = blockIdx.x, c = threadIdx.x;
  const float* p = eig + (size_t)f * 256 * 768 + c;
  float s0 = 0.f, s1 = 0.f, s2 = 0.f, s3 = 0.f;
  for (int px = 0; px < 256; px += 4) {
    s0 += p[(size_t)px * 768];
    s1 += p[(size_t)(px + 1) * 768];
    s2 += p[(size_t)(px + 2) * 768];
    s3 += p[(size_t)(px + 3) * 768];
  }
  const float tot = (s0 + s1 + s2 + s3) * (1.0f / 256.0f);
  if (c < 384) mr[f * 384 + c] = tot;
  else         mi[f * 384 + c - 384] = tot;
}

// ==================== flux scan + operator precompute ====================
__global__ __launch_bounds__(384) void flux_kernel(
    const float* __restrict__ dt, const float* __restrict__ lamf,
    const float* __restrict__ nu, const float* __restrict__ omega,
    const float* __restrict__ mr, const float* __restrict__ mi,
    float* __restrict__ fluxr, float* __restrict__ fluxi,
    float* __restrict__ opdr, float* __restrict__ opdi,
    float* __restrict__ opfr, float* __restrict__ opfi) {
  const int b = blockIdx.x;
  const int d = threadIdx.x;
  const float sp = softplus_f(lamf[d]);
  float lre = -softplus_f(nu[d]);
  lre = fmaxf(lre, -5.0f);
  const float lim = omega[d];
  const float den = lre * lre + lim * lim;
  float fr = 0.f, fi = 0.f;
  for (int t = 0; t < 12; ++t) {
    const float dtv = dt[b * 12 + t];
    const int idx = (b * 12 + t) * 384 + d;
    const float A = expf(-sp * dtv);
    fr = A * fr + mr[idx] * dtv;
    fi = A * fi + mi[idx] * dtv;
    fluxr[idx] = fr; fluxi[idx] = fi;
    const float ed = expf(lre * dtv);
    const float odr = ed * cosf(lim * dtv);
    const float odi = ed * sinf(lim * dtv);
    opdr[idx] = odr; opdi[idx] = odi;
    const float nr_ = odr - 1.0f, ni_ = odi;
    opfr[idx] = (nr_ * lre + ni_ * lim) / den;
    opfi[idx] = (ni_ * lre - nr_ * lim) / den;
  }
}

// ==================== small fp32 complex GEMM (M=48 source term) ====================
#define SBM 64
#define SBN 64
#define SBK 32
__global__ __launch_bounds__(256) void cgemm_small_kernel(
    const float* __restrict__ Ar, const float* __restrict__ Ai, int lda,
    const float* __restrict__ Wr, const float* __restrict__ Wi, int ldw,
    float* __restrict__ Cr, float* __restrict__ Ci, int ldc, int M, int K) {
  __shared__ float Asr[SBK][SBM], Asi[SBK][SBM];
  __shared__ float Wsr[SBK][SBN], Wsi[SBK][SBN];
  const int m0 = blockIdx.x * SBM;
  const int n0 = blockIdx.y * SBN;
  const int tid = threadIdx.x;
  const int tn = tid & 15, tm = tid >> 4;
  float accr[4][4] = {}, acci[4][4] = {};
  for (int k0 = 0; k0 < K; k0 += SBK) {
    for (int s = tid; s < 512; s += 256) {
      {
        int r = s >> 3, kk = (s & 7) << 2;
        int row = m0 + r;
        float4 vr = {0.f, 0.f, 0.f, 0.f}, vi = {0.f, 0.f, 0.f, 0.f};
        if (row < M) {
          vr = *(const float4*)(Ar + (size_t)row * lda + k0 + kk);
          vi = *(const float4*)(Ai + (size_t)row * lda + k0 + kk);
        }
        Asr[kk + 0][r] = vr.x; Asr[kk + 1][r] = vr.y; Asr[kk + 2][r] = vr.z; Asr[kk + 3][r] = vr.w;
        Asi[kk + 0][r] = vi.x; Asi[kk + 1][r] = vi.y; Asi[kk + 2][r] = vi.z; Asi[kk + 3][r] = vi.w;
      }
      {
        int wr_ = s >> 4, wc = (s & 15) << 2;
        *(float4*)&Wsr[wr_][wc] = *(const float4*)(Wr + (size_t)(k0 + wr_) * ldw + n0 + wc);
        *(float4*)&Wsi[wr_][wc] = *(const float4*)(Wi + (size_t)(k0 + wr_) * ldw + n0 + wc);
      }
    }
    __syncthreads();
#pragma unroll
    for (int kk = 0; kk < SBK; ++kk) {
      float4 ar4 = *(const float4*)&Asr[kk][tm << 2];
      float4 ai4 = *(const float4*)&Asi[kk][tm << 2];
      float4 wr4 = *(const float4*)&Wsr[kk][tn << 2];
      float4 wi4 = *(const float4*)&Wsi[kk][tn << 2];
      float ar[4] = {ar4.x, ar4.y, ar4.z, ar4.w};
      float ai[4] = {ai4.x, ai4.y, ai4.z, ai4.w};
      float wr[4] = {wr4.x, wr4.y, wr4.z, wr4.w};
      float wi[4] = {wi4.x, wi4.y, wi4.z, wi4.w};
#pragma unroll
      for (int i = 0; i < 4; ++i)
#pragma unroll
        for (int j = 0; j < 4; ++j) {
          accr[i][j] = fmaf(ar[i], wr[j], accr[i][j]);
          accr[i][j] = fmaf(-ai[i], wi[j], accr[i][j]);
          acci[i][j] = fmaf(ar[i], wi[j], acci[i][j]);
          acci[i][j] = fmaf(ai[i], wr[j], acci[i][j]);
        }
    }
    __syncthreads();
  }
#pragma unroll
  for (int i = 0; i < 4; ++i) {
    int row = m0 + (tm << 2) + i;
    if (row >= M) continue;
#pragma unroll
    for (int j = 0; j < 4; ++j) {
      int col = n0 + (tn << 2) + j;
      size_t idx = (size_t)row * ldc + col;
      Cr[idx] = accr[i][j]; Ci[idx] = acci[i][j];
    }
  }
}

// ==================== forcing + u_t (combined layout, in-place on eig) ====================
__global__ __launch_bounds__(256) void forcing_kernel(
    float* __restrict__ eig, const float* __restrict__ fluxr,
    const float* __restrict__ srcr, const float* __restrict__ srci,
    const float* __restrict__ Wg,
    const float* __restrict__ opfr, const float* __restrict__ opfi) {
  const int g = blockIdx.x * 256 + threadIdx.x;
  if (g >= 12288 * 384) return;
  const int d = g % 384;
  const int row = g / 384;
  const int fidx = (row >> 8) * 384 + d;
  const float gate = 1.0f / (1.0f + expf(-fluxr[fidx] * Wg[d]));
  const size_t ir = (size_t)row * 768 + d;
  const float er = eig[ir], ei = eig[ir + 384];
  const float fr = er * gate + srcr[fidx] * (1.0f - gate);
  const float fi = ei * gate + srci[fidx] * (1.0f - gate);
  const float pr = opfr[fidx], pi = opfi[fidx];
  eig[ir] = fr * pr - fi * pi;
  eig[ir + 384] = fr * pi + fi * pr;
}

// ==================== u_out pscan over T -> bf16 ub (combined) ====================
__global__ __launch_bounds__(256) void pscan_u_kernel(
    const float* __restrict__ eig,
    const float* __restrict__ opdr, const float* __restrict__ opdi,
    u16* __restrict__ ub) {
  const int g = blockIdx.x * 256 + threadIdx.x;
  if (g >= 4 * 256 * 384) return;
  const int d = g % 384;
  const int pix = (g / 384) & 255;
  const int b = g / (384 * 256);
  float ur = 0.f, ui = 0.f;
  for (int t = 0; t < 12; ++t) {
    const int frame = b * 12 + t;
    const size_t idx = ((size_t)frame * 256 + pix) * 768 + d;
    const int fidx = frame * 384 + d;
    const float ar = opdr[fidx], ai = opdi[fidx];
    const float nr = ar * ur - ai * ui + eig[idx];
    const float ni = ar * ui + ai * ur + eig[idx + 384];
    ub[idx] = f2bf(nr); ub[idx + 384] = f2bf(ni);
    ur = nr; ui = ni;
  }
}

// ==================== z += df (vectorized) ====================
__global__ __launch_bounds__(256) void add_df_kernel(
    float* __restrict__ z, const float* __restrict__ df, int n4) {
  const int g = blockIdx.x * 256 + threadIdx.x;
  if (g < n4) {
    float4 a = *(const float4*)(z + (size_t)g * 4);
    const float4 b = *(const float4*)(df + (size_t)g * 4);
    a.x += b.x; a.y += b.y; a.z += b.z; a.w += b.w;
    *(float4*)(z + (size_t)g * 4) = a;
  }
}

extern "C" void kernel_launch(void* const* d_in, const int* in_sizes, int n_in,
                              void* d_out, int out_size, void* d_ws, size_t ws_size,
                              hipStream_t stream) {
  const float* x        = (const float*)d_in[0];
  const float* dt       = (const float*)d_in[1];
  const float* enc_w    = (const float*)d_in[2];
  const float* enc_b    = (const float*)d_in[3];
  const float* ns_g     = (const float*)d_in[4];
  const float* ns_b     = (const float*)d_in[5];
  const float* cw       = (const float*)d_in[6];
  const float* cb       = (const float*)d_in[7];
  const float* nt_g     = (const float*)d_in[8];
  const float* nt_b     = (const float*)d_in[9];
  const float* E_re     = (const float*)d_in[10];
  const float* E_im     = (const float*)d_in[11];
  const float* Ei_re    = (const float*)d_in[12];
  const float* Ei_im    = (const float*)d_in[13];
  const float* lam_flux = (const float*)d_in[14];
  const float* Ws_re    = (const float*)d_in[15];
  const float* Ws_im    = (const float*)d_in[16];
  const float* Wg       = (const float*)d_in[17];
  const float* nu       = (const float*)d_in[18];
  const float* omega    = (const float*)d_in[19];
  const float* w1_re    = (const float*)d_in[20];
  const float* w1_im    = (const float*)d_in[21];
  const float* w2_re    = (const float*)d_in[22];
  const float* w2_im    = (const float*)d_in[23];
  const float* dec_w    = (const float*)d_in[24];
  const float* dec_b    = (const float*)d_in[25];
  float* out = (float*)d_out;

  const size_t NPF = 12288ull * 768;        // 9,437,184
  const size_t XNP = 48ull * 324 * 768;     // 11,943,936 (halo-padded plane)
  const size_t SM = 48ull * 384;

  float* z   = (float*)d_ws;                 // [12288][768] fp32 residual master
  float* eig = z + NPF;                      // fp32; aliased by h1b (bf16 [12288][1536])
  float* df  = eig + NPF;                    // fp32; first half aliased by zb (bf16)
  u16* xnp   = (u16*)(df + NPF);             // halo xnbp / flat xnb / ub (disjoint lifetimes)
  u16* Btc   = xnp + XNP;                    // [768][6912]
  u16* Et    = Btc + 5308416;                // [768][768]
  u16* Eit   = Et + 589824;
  u16* W1t   = Eit + 589824;                 // 2 chunks x [1536][768]
  u16* W2t   = W1t + 2359296;                // 2 chunks x [768][1536]
  u16* dwt   = W2t + 2359296;                // [1024][768]
  float* sm  = (float*)(dwt + 786432);
  float* mr    = sm;            float* mi    = mr + SM;
  float* fluxr = mi + SM;       float* fluxi = fluxr + SM;
  float* opdr  = fluxi + SM;    float* opdi  = opdr + SM;
  float* opfr  = opdi + SM;     float* opfi  = opfr + SM;
  float* srcr  = opfi + SM;     float* srci  = srcr + SM;

  const size_t need = ((char*)(srci + SM)) - ((char*)d_ws);
  if (ws_size < need) return;

  u16* zb  = (u16*)df;    // bf16 shadow of z (dead when df written)
  u16* h1b = (u16*)eig;   // FFN hidden chunk [12288][1536] bf16 (eig dead after pscan)

  // decoder weight cast (dec_w is already [1024][768] = [N][K])
  cast_bf16_kernel<<<(786432 + 255) / 256, 256, 0, stream>>>(dec_w, dwt, 786432);

  encoder_mfma_kernel<<<dim3(96, 6), 256, 0, stream>>>(x, enc_w, enc_b, z);

  for (int l = 0; l < 4; ++l) {
    const size_t DD = 384ull * 384, DF = 384ull * 1536;
    hipMemsetAsync(xnp, 0, XNP * sizeof(u16), stream);  // zero halo borders
    reorder_cw_kernel<<<768, 256, 0, stream>>>(cw + (size_t)l * 768 * 768 * 9, Btc);
    expand_kernel<<<dim3(24, 24), 256, 0, stream>>>(E_re + l * DD, E_im + l * DD, 384, 384, 384, Et);
    expand_kernel<<<dim3(24, 24), 256, 0, stream>>>(Ei_re + l * DD, Ei_im + l * DD, 384, 384, 384, Eit);
    for (int ch = 0; ch < 2; ++ch) {
      expand_kernel<<<dim3(24, 48), 256, 0, stream>>>(
          w1_re + l * DF + ch * 768, w1_im + l * DF + ch * 768, 1536, 384, 768, W1t + (size_t)ch * 1179648);
      expand_kernel<<<dim3(48, 24), 256, 0, stream>>>(
          w2_re + l * DF + (size_t)ch * 768 * 384, w2_im + l * DF + (size_t)ch * 768 * 384, 384, 768, 384,
          W2t + (size_t)ch * 1179648);
    }

    ln_kernel<true><<<12288, 192, 0, stream>>>(z, ns_g + l * 768, ns_b + l * 768, xnp);
    conv_mfma128_kernel<<<dim3(96, 6), 256, 0, stream>>>(xnp, Btc, cb + l * 768, z, zb);
    gemm128_kernel<0><<<dim3(96, 6), 256, 0, stream>>>(zb, Et, 768, 768, eig, nullptr, nullptr);
    mean_kernel<<<48, 768, 0, stream>>>(eig, mr, mi);
    flux_kernel<<<4, 384, 0, stream>>>(dt, lam_flux + l * 384, nu + l * 384, omega + l * 384,
                                       mr, mi, fluxr, fluxi, opdr, opdi, opfr, opfi);
    cgemm_small_kernel<<<dim3(1, 6), 256, 0, stream>>>(
        fluxr, fluxi, 384, Ws_re + l * DD, Ws_im + l * DD, 384, srcr, srci, 384, 48, 384);
    forcing_kernel<<<(12288 * 384 + 255) / 256, 256, 0, stream>>>(
        eig, fluxr, srcr, srci, Wg + l * 384, opfr, opfi);
    pscan_u_kernel<<<1536, 256, 0, stream>>>(eig, opdr, opdi, xnp);  // ub = xnp (flat)
    gemm128_kernel<0><<<dim3(96, 6), 256, 0, stream>>>(xnp, Eit, 768, 768, df, nullptr, nullptr);
    ln_kernel<false><<<12288, 192, 0, stream>>>(df, nt_g + l * 768, nt_b + l * 768, xnp);  // xnb = xnp
    add_df_kernel<<<(int)((NPF / 4 + 255) / 256), 256, 0, stream>>>(z, df, (int)(NPF / 4));
    for (int ch = 0; ch < 2; ++ch) {
      gemm128_kernel<1><<<dim3(96, 12), 256, 0, stream>>>(
          xnp, W1t + (size_t)ch * 1179648, 768, 1536, nullptr, h1b, nullptr);
      gemm128_kernel<2><<<dim3(96, 6), 256, 0, stream>>>(
          h1b, W2t + (size_t)ch * 1179648, 1536, 768, z, nullptr, nullptr);
    }
  }

  // final: zb = bf16(z); decoder GEMM + patch scatter
  cast_bf16_kernel<<<(int)((NPF + 255) / 256), 256, 0, stream>>>(z, zb, (int)NPF);
  gemm128_kernel<3><<<dim3(96, 8), 256, 0, stream>>>(zb, dwt, 768, 0, out, nullptr, dec_b);
}

// Round 4
// 2925.924 us; speedup vs baseline: 5.7355x; 1.0097x over previous
//
#include <hip/hip_runtime.h>
#include <cstddef>
#include <cstdint>

typedef unsigned short u16;
typedef short bf16x8 __attribute__((ext_vector_type(8)));
typedef float f32x4 __attribute__((ext_vector_type(4)));

__device__ __forceinline__ float gelu_tanh(float x) {
  float x3 = x * x * x;
  float t = tanhf(0.7978845608028654f * (x + 0.044715f * x3));
  return 0.5f * x * (1.0f + t);
}
__device__ __forceinline__ float softplus_f(float x) {
  return (x > 20.0f) ? x : log1pf(expf(x));
}
__device__ __forceinline__ u16 f2bf(float f) {
  uint32_t u = __float_as_uint(f);
  uint32_t r = (u + 0x7fffu + ((u >> 16) & 1u)) >> 16;
  return (u16)r;
}

// async global->LDS, 16B/lane; LDS dest = wave-uniform base + lane*16
__device__ __forceinline__ void gload16(const u16* g, u16* l) {
  __builtin_amdgcn_global_load_lds(
      (const __attribute__((address_space(1))) void*)g,
      (__attribute__((address_space(3))) void*)l, 16, 0, 0);
}

// ==================== unified MFMA GEMM, 128xTN tile, two-panel BK=64 ====================
// A [M][K] bf16 row-major; Bt [N][K] bf16.
// MODE 0: Cf = v              MODE 1: Cb = bf16(gelu(v))
// MODE 2: Cf += v             MODE 3: decoder scatter out = v + bias
// MODE 4: Cf += v + Df        MODE 5: Cf += v; Cb = bf16(Cf)
template <int TN, int MODE>
__global__ __launch_bounds__(256) void gemm_kernel(
    const u16* __restrict__ A, const u16* __restrict__ Bt, int K, int ldc,
    float* __restrict__ Cf, u16* __restrict__ Cb,
    const float* __restrict__ bias, const float* __restrict__ Df) {
  __shared__ u16 As[2][128 * 32];
  __shared__ u16 Bs[2][TN * 32];
  constexpr int NI = (TN == 64) ? 2 : 4;
  const int m0 = blockIdx.x * 128, n0 = blockIdx.y * TN;
  const int tid = threadIdx.x;
  const int lane = tid & 63, w = tid >> 6;
  const int lane15 = lane & 15, quad = lane >> 4;
  const int r0 = lane >> 2, e0 = (lane & 3) * 8;
  const int wy = (TN == 64) ? w : (w >> 1);
  const int wx = (TN == 64) ? 0 : (w & 1);

  const u16* ag0 = A + (size_t)(m0 + w * 32 + r0) * K + e0;
  const u16* ag1 = ag0 + (size_t)16 * K;
  const u16* bg0 = (TN == 64) ? Bt + (size_t)(n0 + w * 16 + r0) * K + e0
                              : Bt + (size_t)(n0 + w * 32 + r0) * K + e0;
  const u16* bg1 = bg0 + (size_t)16 * K;

  f32x4 acc[NI][4] = {};
  const int abase = (wy * (16 * NI) + lane15) * 32 + quad * 8;
  const int bbase = (wx * 64 + lane15) * 32 + quad * 8;

  for (int k0 = 0; k0 < K; k0 += 64) {
#pragma unroll
    for (int p = 0; p < 2; ++p) {
      const int kk = k0 + 32 * p;
      gload16(ag0 + kk, &As[p][w * 1024]);
      gload16(ag1 + kk, &As[p][w * 1024 + 512]);
      if (TN == 64) {
        gload16(bg0 + kk, &Bs[p][w * 512]);
      } else {
        gload16(bg0 + kk, &Bs[p][w * 1024]);
        gload16(bg1 + kk, &Bs[p][w * 1024 + 512]);
      }
    }
    __syncthreads();
#pragma unroll
    for (int p = 0; p < 2; ++p) {
      bf16x8 af[NI], bf[4];
#pragma unroll
      for (int i = 0; i < NI; ++i) af[i] = *(const bf16x8*)&As[p][abase + i * 16 * 32];
#pragma unroll
      for (int j = 0; j < 4; ++j) bf[j] = *(const bf16x8*)&Bs[p][bbase + j * 16 * 32];
#pragma unroll
      for (int i = 0; i < NI; ++i)
#pragma unroll
        for (int j = 0; j < 4; ++j)
          acc[i][j] = __builtin_amdgcn_mfma_f32_16x16x32_bf16(af[i], bf[j], acc[i][j], 0, 0, 0);
    }
    __syncthreads();
  }

  const int mw = m0 + wy * (16 * NI), nw = n0 + wx * 64;
#pragma unroll
  for (int i = 0; i < NI; ++i) {
#pragma unroll
    for (int j = 0; j < 4; ++j) {
      const int col = nw + j * 16 + lane15;
#pragma unroll
      for (int r = 0; r < 4; ++r) {
        const int row = mw + i * 16 + quad * 4 + r;
        const float v = acc[i][j][r];
        const size_t idx = (size_t)row * ldc + col;
        if (MODE == 0) {
          Cf[idx] = v;
        } else if (MODE == 1) {
          Cb[idx] = f2bf(gelu_tanh(v));
        } else if (MODE == 2) {
          Cf[idx] += v;
        } else if (MODE == 3) {
          const int frame = row >> 8, pix = row & 255;
          const int hp = pix >> 4, wp = pix & 15;
          const int co = col >> 8, p1 = (col >> 4) & 15, p2 = col & 15;
          Cf[(((size_t)frame * 4 + co) * 256 + hp * 16 + p1) * 256 + wp * 16 + p2] = v + bias[col];
        } else if (MODE == 4) {
          Cf[idx] += v + Df[idx];
        } else if (MODE == 5) {
          const float nz = Cf[idx] + v;
          Cf[idx] = nz;
          Cb[idx] = f2bf(nz);
        }
      }
    }
  }
}

// ==================== conv3x3 implicit-GEMM, 128x64 tile, two-panel ====================
__global__ __launch_bounds__(256) void conv_mfma_kernel(
    const u16* __restrict__ xnp, const u16* __restrict__ Btc,
    const float* __restrict__ cbias,
    float* __restrict__ z, u16* __restrict__ zb) {
  __shared__ u16 As[2][128 * 32];
  __shared__ u16 Bs[2][64 * 32];
  const int m0 = blockIdx.x * 128, n0 = blockIdx.y * 64;
  const int tid = threadIdx.x;
  const int lane = tid & 63, w = tid >> 6;
  const int lane15 = lane & 15, quad = lane >> 4;
  const int r0 = lane >> 2, e0 = (lane & 3) * 8;

  const int rowA0 = m0 + w * 32 + r0, rowA1 = rowA0 + 16;
  const long long cen0 = ((long long)(rowA0 >> 8) * 324 + ((((rowA0 & 255) >> 4) + 1) * 18) + (rowA0 & 15) + 1) * 768 + e0;
  const long long cen1 = ((long long)(rowA1 >> 8) * 324 + ((((rowA1 & 255) >> 4) + 1) * 18) + (rowA1 & 15) + 1) * 768 + e0;
  const u16* bg = Btc + (size_t)(n0 + w * 16 + r0) * 6912 + e0;

  f32x4 acc[2][4] = {};
  const int abase = (w * 32 + lane15) * 32 + quad * 8;
  const int bbase = (lane15) * 32 + quad * 8;

  for (int tap = 0; tap < 9; ++tap) {
    const int doff = ((tap / 3 - 1) * 18 + (tap % 3 - 1)) * 768;
    const u16* a0 = xnp + cen0 + doff;
    const u16* a1 = xnp + cen1 + doff;
    const u16* b0 = bg + tap * 768;
    for (int kc = 0; kc < 768; kc += 64) {
#pragma unroll
      for (int p = 0; p < 2; ++p) {
        const int kk = kc + 32 * p;
        gload16(a0 + kk, &As[p][w * 1024]);
        gload16(a1 + kk, &As[p][w * 1024 + 512]);
        gload16(b0 + kk, &Bs[p][w * 512]);
      }
      __syncthreads();
#pragma unroll
      for (int p = 0; p < 2; ++p) {
        bf16x8 af[2], bf[4];
#pragma unroll
        for (int i = 0; i < 2; ++i) af[i] = *(const bf16x8*)&As[p][abase + i * 16 * 32];
#pragma unroll
        for (int j = 0; j < 4; ++j) bf[j] = *(const bf16x8*)&Bs[p][bbase + j * 16 * 32];
#pragma unroll
        for (int i = 0; i < 2; ++i)
#pragma unroll
          for (int j = 0; j < 4; ++j)
            acc[i][j] = __builtin_amdgcn_mfma_f32_16x16x32_bf16(af[i], bf[j], acc[i][j], 0, 0, 0);
      }
      __syncthreads();
    }
  }

  const int mw = m0 + w * 32;
#pragma unroll
  for (int i = 0; i < 2; ++i) {
#pragma unroll
    for (int j = 0; j < 4; ++j) {
      const int col = n0 + j * 16 + lane15;
      const float bv = cbias[col];
#pragma unroll
      for (int r = 0; r < 4; ++r) {
        const int row = mw + i * 16 + quad * 4 + r;
        const size_t idx = (size_t)row * 768 + col;
        const float nz = z[idx] + acc[i][j][r] + bv;
        z[idx] = nz;
        zb[idx] = f2bf(nz);
      }
    }
  }
}

// ==================== encoder: patch-embed MFMA (fp32->bf16 staging, runs once) ====================
__global__ __launch_bounds__(256) void encoder_mfma_kernel(
    const float* __restrict__ x, const float* __restrict__ ew,
    const float* __restrict__ eb, float* __restrict__ z) {
  __shared__ u16 As[128 * 32];
  __shared__ u16 Bs[128 * 32];
  const int m0 = blockIdx.x * 128, n0 = blockIdx.y * 128;
  const int tid = threadIdx.x;
  const int lane = tid & 63, w = tid >> 6;
  const int lane15 = lane & 15, quad = lane >> 4;
  const int srow = tid >> 1, half = tid & 1;
  const int arow = m0 + srow;
  const int frame = arow >> 8, pix = arow & 255, hh = pix >> 4, ww = pix & 15;

  f32x4 acc[4][4] = {};
  const int wy = w >> 1, wx = w & 1;
  const int ar_base = (wy * 64 + lane15) * 32 + quad * 8;
  const int br_base = (wx * 64 + lane15) * 32 + quad * 8;

  for (int k0 = 0; k0 < 1024; k0 += 32) {
    const int gk = k0 + half * 16;
    const int c = gk >> 8, ph = (gk >> 4) & 15;
    const float* ax = x + (((size_t)(frame * 4 + c) * 256 + hh * 16 + ph) * 256 + ww * 16);
    const float* bx = ew + (size_t)(n0 + srow) * 1024 + gk;
    u16 ta[16], tb[16];
#pragma unroll
    for (int j = 0; j < 4; ++j) {
      const float4 va = *(const float4*)(ax + j * 4);
      const float4 vb = *(const float4*)(bx + j * 4);
      ta[j * 4 + 0] = f2bf(va.x); ta[j * 4 + 1] = f2bf(va.y);
      ta[j * 4 + 2] = f2bf(va.z); ta[j * 4 + 3] = f2bf(va.w);
      tb[j * 4 + 0] = f2bf(vb.x); tb[j * 4 + 1] = f2bf(vb.y);
      tb[j * 4 + 2] = f2bf(vb.z); tb[j * 4 + 3] = f2bf(vb.w);
    }
    __syncthreads();
    *(uint4*)&As[srow * 32 + half * 16] = *(uint4*)ta;
    *(uint4*)&As[srow * 32 + half * 16 + 8] = *(uint4*)(ta + 8);
    *(uint4*)&Bs[srow * 32 + half * 16] = *(uint4*)tb;
    *(uint4*)&Bs[srow * 32 + half * 16 + 8] = *(uint4*)(tb + 8);
    __syncthreads();
    bf16x8 af[4], bfv[4];
#pragma unroll
    for (int i = 0; i < 4; ++i) af[i] = *(const bf16x8*)&As[ar_base + i * 16 * 32];
#pragma unroll
    for (int j = 0; j < 4; ++j) bfv[j] = *(const bf16x8*)&Bs[br_base + j * 16 * 32];
#pragma unroll
    for (int i = 0; i < 4; ++i)
#pragma unroll
      for (int j = 0; j < 4; ++j)
        acc[i][j] = __builtin_amdgcn_mfma_f32_16x16x32_bf16(af[i], bfv[j], acc[i][j], 0, 0, 0);
  }

  const int mw = m0 + wy * 64, nw = n0 + wx * 64;
#pragma unroll
  for (int i = 0; i < 4; ++i)
#pragma unroll
    for (int j = 0; j < 4; ++j) {
      const int col = nw + j * 16 + lane15;
      const float bv = eb[col];
#pragma unroll
      for (int r = 0; r < 4; ++r) {
        const int row = mw + i * 16 + quad * 4 + r;
        z[(size_t)row * 768 + col] = acc[i][j][r] + bv;
      }
    }
}

// ==================== weight prep ====================
__global__ __launch_bounds__(256) void expand_kernel(
    const float* __restrict__ Wre, const float* __restrict__ Wim,
    int ldw, int Kc, int Nc, u16* __restrict__ Wt) {
  __shared__ float tile[32][33];
  const int k0 = blockIdx.x * 32, n0 = blockIdx.y * 32;
  const bool khi = k0 >= Kc, nhi = n0 >= Nc;
  const float* src = (khi != nhi) ? Wim : Wre;
  const float sgn = (!nhi && khi) ? -1.0f : 1.0f;
  const int sk = k0 - (khi ? Kc : 0), sn = n0 - (nhi ? Nc : 0);
  const int c = threadIdx.x & 31, r8 = threadIdx.x >> 5;
  for (int r = r8; r < 32; r += 8)
    tile[r][c] = src[(size_t)(sk + r) * ldw + sn + c];
  __syncthreads();
  const int twoK = 2 * Kc;
  for (int r = r8; r < 32; r += 8)
    Wt[(size_t)(n0 + r) * twoK + k0 + c] = f2bf(sgn * tile[c][r]);
}

__global__ __launch_bounds__(256) void reorder_cw_kernel(
    const float* __restrict__ cwl, u16* __restrict__ Btc) {
  __shared__ float buf[6912];
  const int o = blockIdx.x;
  const float* src = cwl + (size_t)o * 6912;
  for (int i = threadIdx.x; i < 6912; i += 256) buf[i] = src[i];
  __syncthreads();
  u16* dst = Btc + (size_t)o * 6912;
  for (int i = threadIdx.x; i < 6912; i += 256) {
    const int tap = i / 768, cc = i - tap * 768;
    dst[i] = f2bf(buf[cc * 9 + tap]);
  }
}

__global__ __launch_bounds__(256) void cast_bf16_kernel(
    const float* __restrict__ in, u16* __restrict__ out, int n) {
  const int g = blockIdx.x * 256 + threadIdx.x;
  if (g < n) out[g] = f2bf(in[g]);
}

// ==================== LayerNorm (contiguous 768) ====================
template <bool HALO>
__global__ __launch_bounds__(192) void ln_kernel(
    const float* __restrict__ in, const float* __restrict__ g,
    const float* __restrict__ b, u16* __restrict__ out) {
  const int row = blockIdx.x, tid = threadIdx.x;
  const float4 v = *(const float4*)(in + (size_t)row * 768 + tid * 4);
  float s = v.x + v.y + v.z + v.w;
  float q = v.x * v.x + v.y * v.y + v.z * v.z + v.w * v.w;
#pragma unroll
  for (int off = 32; off > 0; off >>= 1) {
    s += __shfl_down(s, off);
    q += __shfl_down(q, off);
  }
  __shared__ float rs[3], rq[3];
  if ((tid & 63) == 0) { rs[tid >> 6] = s; rq[tid >> 6] = q; }
  __syncthreads();
  const float S = rs[0] + rs[1] + rs[2], Q = rq[0] + rq[1] + rq[2];
  const float mean = S * (1.0f / 768.0f);
  const float inv = rsqrtf(Q * (1.0f / 768.0f) - mean * mean + 1e-5f);
  const float4 gv = *(const float4*)(g + tid * 4);
  const float4 bv = *(const float4*)(b + tid * 4);
  u16 p[4];
  p[0] = f2bf((v.x - mean) * inv * gv.x + bv.x);
  p[1] = f2bf((v.y - mean) * inv * gv.y + bv.y);
  p[2] = f2bf((v.z - mean) * inv * gv.z + bv.z);
  p[3] = f2bf((v.w - mean) * inv * gv.w + bv.w);
  size_t base;
  if (HALO) {
    const int f = row >> 8, pp = row & 255, h = pp >> 4, ww = pp & 15;
    base = ((size_t)f * 324 + (h + 1) * 18 + ww + 1) * 768;
  } else {
    base = (size_t)row * 768;
  }
  *(uint2*)(out + base + tid * 4) = *(uint2*)p;
}

// ==================== mean over 256 pixels ====================
__global__ __launch_bounds__(768) void mean_kernel(
    const float* __restrict__ eig, float* __restrict__ mr, float* __restrict__ mi) {
  const int f = blockIdx.x, c = threadIdx.x;
  const float* p = eig + (size_t)f * 256 * 768 + c;
  float s0 = 0.f, s1 = 0.f, s2 = 0.f, s3 = 0.f;
  for (int px = 0; px < 256; px += 4) {
    s0 += p[(size_t)px * 768];
    s1 += p[(size_t)(px + 1) * 768];
    s2 += p[(size_t)(px + 2) * 768];
    s3 += p[(size_t)(px + 3) * 768];
  }
  const float tot = (s0 + s1 + s2 + s3) * (1.0f / 256.0f);
  if (c < 384) mr[f * 384 + c] = tot;
  else         mi[f * 384 + c - 384] = tot;
}

// ==================== flux scan + operator precompute ====================
__global__ __launch_bounds__(384) void flux_kernel(
    const float* __restrict__ dt, const float* __restrict__ lamf,
    const float* __restrict__ nu, const float* __restrict__ omega,
    const float* __restrict__ mr, const float* __restrict__ mi,
    float* __restrict__ fluxr, float* __restrict__ fluxi,
    float* __restrict__ opdr, float* __restrict__ opdi,
    float* __restrict__ opfr, float* __restrict__ opfi) {
  const int b = blockIdx.x;
  const int d = threadIdx.x;
  const float sp = softplus_f(lamf[d]);
  float lre = -softplus_f(nu[d]);
  lre = fmaxf(lre, -5.0f);
  const float lim = omega[d];
  const float den = lre * lre + lim * lim;
  float fr = 0.f, fi = 0.f;
  for (int t = 0; t < 12; ++t) {
    const float dtv = dt[b * 12 + t];
    const int idx = (b * 12 + t) * 384 + d;
    const float A = expf(-sp * dtv);
    fr = A * fr + mr[idx] * dtv;
    fi = A * fi + mi[idx] * dtv;
    fluxr[idx] = fr; fluxi[idx] = fi;
    const float ed = expf(lre * dtv);
    const float odr = ed * cosf(lim * dtv);
    const float odi = ed * sinf(lim * dtv);
    opdr[idx] = odr; opdi[idx] = odi;
    const float nr_ = odr - 1.0f, ni_ = odi;
    opfr[idx] = (nr_ * lre + ni_ * lim) / den;
    opfi[idx] = (ni_ * lre - nr_ * lim) / den;
  }
}

// ==================== small fp32 complex GEMM + gate-product epilogue ====================
// Computes src = flux*Ws, then G = sigmoid(fluxr*Wg), SG = src*(1-G)
#define SBM 64
#define SBN 64
#define SBK 32
__global__ __launch_bounds__(256) void cgemm_src_kernel(
    const float* __restrict__ Ar, const float* __restrict__ Ai, int lda,
    const float* __restrict__ Wr, const float* __restrict__ Wi, int ldw,
    const float* __restrict__ Wg,
    float* __restrict__ G, float* __restrict__ SGr, float* __restrict__ SGi,
    int ldc, int M, int K) {
  __shared__ float Asr[SBK][SBM], Asi[SBK][SBM];
  __shared__ float Wsr[SBK][SBN], Wsi[SBK][SBN];
  const int m0 = blockIdx.x * SBM;
  const int n0 = blockIdx.y * SBN;
  const int tid = threadIdx.x;
  const int tn = tid & 15, tm = tid >> 4;
  float accr[4][4] = {}, acci[4][4] = {};
  for (int k0 = 0; k0 < K; k0 += SBK) {
    for (int s = tid; s < 512; s += 256) {
      {
        int r = s >> 3, kk = (s & 7) << 2;
        int row = m0 + r;
        float4 vr = {0.f, 0.f, 0.f, 0.f}, vi = {0.f, 0.f, 0.f, 0.f};
        if (row < M) {
          vr = *(const float4*)(Ar + (size_t)row * lda + k0 + kk);
          vi = *(const float4*)(Ai + (size_t)row * lda + k0 + kk);
        }
        Asr[kk + 0][r] = vr.x; Asr[kk + 1][r] = vr.y; Asr[kk + 2][r] = vr.z; Asr[kk + 3][r] = vr.w;
        Asi[kk + 0][r] = vi.x; Asi[kk + 1][r] = vi.y; Asi[kk + 2][r] = vi.z; Asi[kk + 3][r] = vi.w;
      }
      {
        int wr_ = s >> 4, wc = (s & 15) << 2;
        *(float4*)&Wsr[wr_][wc] = *(const float4*)(Wr + (size_t)(k0 + wr_) * ldw + n0 + wc);
        *(float4*)&Wsi[wr_][wc] = *(const float4*)(Wi + (size_t)(k0 + wr_) * ldw + n0 + wc);
      }
    }
    __syncthreads();
#pragma unroll
    for (int kk = 0; kk < SBK; ++kk) {
      float4 ar4 = *(const float4*)&Asr[kk][tm << 2];
      float4 ai4 = *(const float4*)&Asi[kk][tm << 2];
      float4 wr4 = *(const float4*)&Wsr[kk][tn << 2];
      float4 wi4 = *(const float4*)&Wsi[kk][tn << 2];
      float ar[4] = {ar4.x, ar4.y, ar4.z, ar4.w};
      float ai[4] = {ai4.x, ai4.y, ai4.z, ai4.w};
      float wr[4] = {wr4.x, wr4.y, wr4.z, wr4.w};
      float wi[4] = {wi4.x, wi4.y, wi4.z, wi4.w};
#pragma unroll
      for (int i = 0; i < 4; ++i)
#pragma unroll
        for (int j = 0; j < 4; ++j) {
          accr[i][j] = fmaf(ar[i], wr[j], accr[i][j]);
          accr[i][j] = fmaf(-ai[i], wi[j], accr[i][j]);
          acci[i][j] = fmaf(ar[i], wi[j], acci[i][j]);
          acci[i][j] = fmaf(ai[i], wr[j], acci[i][j]);
        }
    }
    __syncthreads();
  }
#pragma unroll
  for (int i = 0; i < 4; ++i) {
    int row = m0 + (tm << 2) + i;
    if (row >= M) continue;
#pragma unroll
    for (int j = 0; j < 4; ++j) {
      int col = n0 + (tn << 2) + j;
      size_t idx = (size_t)row * ldc + col;
      // gate products for the fused forcing+pscan
      const float gate = 1.0f / (1.0f + expf(-/*fluxr*/ Ar[idx] * Wg[col]));
      G[idx] = gate;
      SGr[idx] = accr[i][j] * (1.0f - gate);
      SGi[idx] = acci[i][j] * (1.0f - gate);
    }
  }
}

// ==================== fused forcing + u_out pscan -> bf16 ub ====================
__global__ __launch_bounds__(256) void pscan_fused_kernel(
    const float* __restrict__ eig,
    const float* __restrict__ Gv,
    const float* __restrict__ SGr, const float* __restrict__ SGi,
    const float* __restrict__ opfr, const float* __restrict__ opfi,
    const float* __restrict__ opdr, const float* __restrict__ opdi,
    u16* __restrict__ ub) {
  const int g = blockIdx.x * 256 + threadIdx.x;
  if (g >= 4 * 256 * 384) return;
  const int d = g % 384;
  const int pix = (g / 384) & 255;
  const int b = g / (384 * 256);
  float ur = 0.f, ui = 0.f;
  for (int t = 0; t < 12; ++t) {
    const int frame = b * 12 + t;
    const size_t idx = ((size_t)frame * 256 + pix) * 768 + d;
    const int fidx = frame * 384 + d;
    const float G = Gv[fidx];
    const float fr = eig[idx] * G + SGr[fidx];
    const float fi = eig[idx + 384] * G + SGi[fidx];
    const float pr = opfr[fidx], pi = opfi[fidx];
    const float utr = fr * pr - fi * pi;
    const float uti = fr * pi + fi * pr;
    const float ar = opdr[fidx], ai = opdi[fidx];
    const float nr = ar * ur - ai * ui + utr;
    const float ni = ar * ui + ai * ur + uti;
    ub[idx] = f2bf(nr); ub[idx + 384] = f2bf(ni);
    ur = nr; ui = ni;
  }
}

extern "C" void kernel_launch(void* const* d_in, const int* in_sizes, int n_in,
                              void* d_out, int out_size, void* d_ws, size_t ws_size,
                              hipStream_t stream) {
  const float* x        = (const float*)d_in[0];
  const float* dt       = (const float*)d_in[1];
  const float* enc_w    = (const float*)d_in[2];
  const float* enc_b    = (const float*)d_in[3];
  const float* ns_g     = (const float*)d_in[4];
  const float* ns_b     = (const float*)d_in[5];
  const float* cw       = (const float*)d_in[6];
  const float* cb       = (const float*)d_in[7];
  const float* nt_g     = (const float*)d_in[8];
  const float* nt_b     = (const float*)d_in[9];
  const float* E_re     = (const float*)d_in[10];
  const float* E_im     = (const float*)d_in[11];
  const float* Ei_re    = (const float*)d_in[12];
  const float* Ei_im    = (const float*)d_in[13];
  const float* lam_flux = (const float*)d_in[14];
  const float* Ws_re    = (const float*)d_in[15];
  const float* Ws_im    = (const float*)d_in[16];
  const float* Wg       = (const float*)d_in[17];
  const float* nu       = (const float*)d_in[18];
  const float* omega    = (const float*)d_in[19];
  const float* w1_re    = (const float*)d_in[20];
  const float* w1_im    = (const float*)d_in[21];
  const float* w2_re    = (const float*)d_in[22];
  const float* w2_im    = (const float*)d_in[23];
  const float* dec_w    = (const float*)d_in[24];
  const float* dec_b    = (const float*)d_in[25];
  float* out = (float*)d_out;

  const size_t NPF = 12288ull * 768;        // 9,437,184
  const size_t XNP = 48ull * 324 * 768;     // 11,943,936 (halo-padded plane)
  const size_t SM = 48ull * 384;

  float* z   = (float*)d_ws;                 // [12288][768] fp32 residual master
  float* eig = z + NPF;                      // fp32; aliased by h1b
  float* df  = eig + NPF;                    // fp32; aliased by zb
  u16* xnp   = (u16*)(df + NPF);             // halo xnbp / flat xnb / ub
  u16* Btc   = xnp + XNP;                    // [768][6912]
  u16* Et    = Btc + 5308416;                // [768][768]
  u16* Eit   = Et + 589824;
  u16* W1t   = Eit + 589824;                 // 2 chunks x [1536][768]
  u16* W2t   = W1t + 2359296;                // 2 chunks x [768][1536]
  u16* dwt   = W2t + 2359296;                // [1024][768]
  float* sm  = (float*)(dwt + 786432);
  float* mr    = sm;            float* mi    = mr + SM;
  float* fluxr = mi + SM;       float* fluxi = fluxr + SM;
  float* opdr  = fluxi + SM;    float* opdi  = opdr + SM;
  float* opfr  = opdi + SM;     float* opfi  = opfr + SM;
  float* Gv    = opfi + SM;     float* SGr   = Gv + SM;
  float* SGi   = SGr + SM;

  const size_t need = ((char*)(SGi + SM)) - ((char*)d_ws);
  if (ws_size < need) return;

  u16* zb  = (u16*)df;    // bf16 shadow of z (df dead at that point)
  u16* h1b = (u16*)eig;   // FFN hidden chunk [12288][1536] bf16 (eig dead after pscan)

  cast_bf16_kernel<<<(786432 + 255) / 256, 256, 0, stream>>>(dec_w, dwt, 786432);
  encoder_mfma_kernel<<<dim3(96, 6), 256, 0, stream>>>(x, enc_w, enc_b, z);

  for (int l = 0; l < 4; ++l) {
    const size_t DD = 384ull * 384, DF = 384ull * 1536;
    hipMemsetAsync(xnp, 0, XNP * sizeof(u16), stream);  // zero halo borders
    reorder_cw_kernel<<<768, 256, 0, stream>>>(cw + (size_t)l * 768 * 768 * 9, Btc);
    expand_kernel<<<dim3(24, 24), 256, 0, stream>>>(E_re + l * DD, E_im + l * DD, 384, 384, 384, Et);
    expand_kernel<<<dim3(24, 24), 256, 0, stream>>>(Ei_re + l * DD, Ei_im + l * DD, 384, 384, 384, Eit);
    for (int ch = 0; ch < 2; ++ch) {
      expand_kernel<<<dim3(24, 48), 256, 0, stream>>>(
          w1_re + l * DF + ch * 768, w1_im + l * DF + ch * 768, 1536, 384, 768, W1t + (size_t)ch * 1179648);
      expand_kernel<<<dim3(48, 24), 256, 0, stream>>>(
          w2_re + l * DF + (size_t)ch * 768 * 384, w2_im + l * DF + (size_t)ch * 768 * 384, 384, 768, 384,
          W2t + (size_t)ch * 1179648);
    }

    ln_kernel<true><<<12288, 192, 0, stream>>>(z, ns_g + l * 768, ns_b + l * 768, xnp);
    conv_mfma_kernel<<<dim3(96, 12), 256, 0, stream>>>(xnp, Btc, cb + l * 768, z, zb);
    gemm_kernel<64, 0><<<dim3(96, 12), 256, 0, stream>>>(zb, Et, 768, 768, eig, nullptr, nullptr, nullptr);
    mean_kernel<<<48, 768, 0, stream>>>(eig, mr, mi);
    flux_kernel<<<4, 384, 0, stream>>>(dt, lam_flux + l * 384, nu + l * 384, omega + l * 384,
                                       mr, mi, fluxr, fluxi, opdr, opdi, opfr, opfi);
    cgemm_src_kernel<<<dim3(1, 6), 256, 0, stream>>>(
        fluxr, fluxi, 384, Ws_re + l * DD, Ws_im + l * DD, 384,
        Wg + l * 384, Gv, SGr, SGi, 384, 48, 384);
    pscan_fused_kernel<<<1536, 256, 0, stream>>>(eig, Gv, SGr, SGi, opfr, opfi, opdr, opdi, xnp);
    gemm_kernel<64, 0><<<dim3(96, 12), 256, 0, stream>>>(xnp, Eit, 768, 768, df, nullptr, nullptr, nullptr);
    ln_kernel<false><<<12288, 192, 0, stream>>>(df, nt_g + l * 768, nt_b + l * 768, xnp);
    for (int ch = 0; ch < 2; ++ch) {
      gemm_kernel<128, 1><<<dim3(96, 12), 256, 0, stream>>>(
          xnp, W1t + (size_t)ch * 1179648, 768, 1536, nullptr, h1b, nullptr, nullptr);
      if (ch == 0) {
        // z += W2 + df (df-residual fused)
        gemm_kernel<64, 4><<<dim3(96, 12), 256, 0, stream>>>(
            h1b, W2t, 1536, 768, z, nullptr, nullptr, df);
      } else if (l < 3) {
        gemm_kernel<64, 2><<<dim3(96, 12), 256, 0, stream>>>(
            h1b, W2t + 1179648, 1536, 768, z, nullptr, nullptr, nullptr);
      } else {
        // final layer: also emit zb for the decoder
        gemm_kernel<64, 5><<<dim3(96, 12), 256, 0, stream>>>(
            h1b, W2t + 1179648, 1536, 768, z, zb, nullptr, nullptr);
      }
    }
  }

  gemm_kernel<64, 3><<<dim3(96, 16), 256, 0, stream>>>(zb, dwt, 768, 0, out, nullptr, dec_b, nullptr);
}

// Round 5
// 2827.818 us; speedup vs baseline: 5.9345x; 1.0347x over previous
//
#include <hip/hip_runtime.h>
#include <cstddef>
#include <cstdint>

typedef unsigned short u16;
typedef short bf16x8 __attribute__((ext_vector_type(8)));
typedef float f32x4 __attribute__((ext_vector_type(4)));

__device__ __forceinline__ float gelu_tanh(float x) {
  float x3 = x * x * x;
  float t = tanhf(0.7978845608028654f * (x + 0.044715f * x3));
  return 0.5f * x * (1.0f + t);
}
__device__ __forceinline__ float softplus_f(float x) {
  return (x > 20.0f) ? x : log1pf(expf(x));
}
__device__ __forceinline__ u16 f2bf(float f) {
  uint32_t u = __float_as_uint(f);
  uint32_t r = (u + 0x7fffu + ((u >> 16) & 1u)) >> 16;
  return (u16)r;
}

// async global->LDS, 16B/lane; LDS dest = wave-uniform base + lane*16
__device__ __forceinline__ void gload16(const u16* g, u16* l) {
  __builtin_amdgcn_global_load_lds(
      (const __attribute__((address_space(1))) void*)g,
      (__attribute__((address_space(3))) void*)l, 16, 0, 0);
}

// ==================== unified MFMA GEMM, 128xTN tile, two-panel BK=64 ====================
// A [M][K] bf16 row-major; Bt [N][K] bf16.
// MODE 0: Cf = v              MODE 1: Cb = bf16(gelu(v))
// MODE 2: Cf += v             MODE 3: decoder scatter out = v + bias
// MODE 4: Cf += v + Df        MODE 5: Cf += v; Cb = bf16(Cf)
template <int TN, int MODE>
__global__ __launch_bounds__(256) void gemm_kernel(
    const u16* __restrict__ A, const u16* __restrict__ Bt, int K, int ldc,
    float* __restrict__ Cf, u16* __restrict__ Cb,
    const float* __restrict__ bias, const float* __restrict__ Df) {
  __shared__ u16 As[2][128 * 32];
  __shared__ u16 Bs[2][TN * 32];
  constexpr int NI = (TN == 64) ? 2 : 4;
  const int m0 = blockIdx.x * 128, n0 = blockIdx.y * TN;
  const int tid = threadIdx.x;
  const int lane = tid & 63, w = tid >> 6;
  const int lane15 = lane & 15, quad = lane >> 4;
  const int r0 = lane >> 2, e0 = (lane & 3) * 8;
  const int wy = (TN == 64) ? w : (w >> 1);
  const int wx = (TN == 64) ? 0 : (w & 1);

  const u16* ag0 = A + (size_t)(m0 + w * 32 + r0) * K + e0;
  const u16* ag1 = ag0 + (size_t)16 * K;
  const u16* bg0 = (TN == 64) ? Bt + (size_t)(n0 + w * 16 + r0) * K + e0
                              : Bt + (size_t)(n0 + w * 32 + r0) * K + e0;
  const u16* bg1 = bg0 + (size_t)16 * K;

  f32x4 acc[NI][4] = {};
  const int abase = (wy * (16 * NI) + lane15) * 32 + quad * 8;
  const int bbase = (wx * 64 + lane15) * 32 + quad * 8;

  for (int k0 = 0; k0 < K; k0 += 64) {
#pragma unroll
    for (int p = 0; p < 2; ++p) {
      const int kk = k0 + 32 * p;
      gload16(ag0 + kk, &As[p][w * 1024]);
      gload16(ag1 + kk, &As[p][w * 1024 + 512]);
      if (TN == 64) {
        gload16(bg0 + kk, &Bs[p][w * 512]);
      } else {
        gload16(bg0 + kk, &Bs[p][w * 1024]);
        gload16(bg1 + kk, &Bs[p][w * 1024 + 512]);
      }
    }
    __syncthreads();
#pragma unroll
    for (int p = 0; p < 2; ++p) {
      bf16x8 af[NI], bf[4];
#pragma unroll
      for (int i = 0; i < NI; ++i) af[i] = *(const bf16x8*)&As[p][abase + i * 16 * 32];
#pragma unroll
      for (int j = 0; j < 4; ++j) bf[j] = *(const bf16x8*)&Bs[p][bbase + j * 16 * 32];
#pragma unroll
      for (int i = 0; i < NI; ++i)
#pragma unroll
        for (int j = 0; j < 4; ++j)
          acc[i][j] = __builtin_amdgcn_mfma_f32_16x16x32_bf16(af[i], bf[j], acc[i][j], 0, 0, 0);
    }
    __syncthreads();
  }

  const int mw = m0 + wy * (16 * NI), nw = n0 + wx * 64;
#pragma unroll
  for (int i = 0; i < NI; ++i) {
#pragma unroll
    for (int j = 0; j < 4; ++j) {
      const int col = nw + j * 16 + lane15;
#pragma unroll
      for (int r = 0; r < 4; ++r) {
        const int row = mw + i * 16 + quad * 4 + r;
        const float v = acc[i][j][r];
        const size_t idx = (size_t)row * ldc + col;
        if (MODE == 0) {
          Cf[idx] = v;
        } else if (MODE == 1) {
          Cb[idx] = f2bf(gelu_tanh(v));
        } else if (MODE == 2) {
          Cf[idx] += v;
        } else if (MODE == 3) {
          const int frame = row >> 8, pix = row & 255;
          const int hp = pix >> 4, wp = pix & 15;
          const int co = col >> 8, p1 = (col >> 4) & 15, p2 = col & 15;
          Cf[(((size_t)frame * 4 + co) * 256 + hp * 16 + p1) * 256 + wp * 16 + p2] = v + bias[col];
        } else if (MODE == 4) {
          Cf[idx] += v + Df[idx];
        } else if (MODE == 5) {
          const float nz = Cf[idx] + v;
          Cf[idx] = nz;
          Cb[idx] = f2bf(nz);
        }
      }
    }
  }
}

// ==================== conv3x3 implicit-GEMM, 128x128 tile, two-panel BK=64 ====================
// Best of both: round-3 locality (6 column-blocks; A/B re-fetch minimized) +
// round-4 barrier amortization (32 MFMA/wave per barrier pair, 108 pairs total).
__global__ __launch_bounds__(256) void conv_mfma_kernel(
    const u16* __restrict__ xnp, const u16* __restrict__ Btc,
    const float* __restrict__ cbias,
    float* __restrict__ z, u16* __restrict__ zb) {
  __shared__ u16 As[2][128 * 32];
  __shared__ u16 Bs[2][128 * 32];
  const int m0 = blockIdx.x * 128, n0 = blockIdx.y * 128;
  const int tid = threadIdx.x;
  const int lane = tid & 63, w = tid >> 6;
  const int lane15 = lane & 15, quad = lane >> 4;
  const int r0 = lane >> 2, e0 = (lane & 3) * 8;

  const int rowA0 = m0 + w * 32 + r0, rowA1 = rowA0 + 16;
  const long long cen0 = ((long long)(rowA0 >> 8) * 324 + ((((rowA0 & 255) >> 4) + 1) * 18) + (rowA0 & 15) + 1) * 768 + e0;
  const long long cen1 = ((long long)(rowA1 >> 8) * 324 + ((((rowA1 & 255) >> 4) + 1) * 18) + (rowA1 & 15) + 1) * 768 + e0;
  const u16* bg0 = Btc + (size_t)(n0 + w * 32 + r0) * 6912 + e0;
  const u16* bg1 = bg0 + (size_t)16 * 6912;

  f32x4 acc[4][4] = {};
  const int wy = w >> 1, wx = w & 1;
  const int abase = (wy * 64 + lane15) * 32 + quad * 8;
  const int bbase = (wx * 64 + lane15) * 32 + quad * 8;

  for (int tap = 0; tap < 9; ++tap) {
    const int doff = ((tap / 3 - 1) * 18 + (tap % 3 - 1)) * 768;
    const u16* a0 = xnp + cen0 + doff;
    const u16* a1 = xnp + cen1 + doff;
    const u16* b0 = bg0 + tap * 768;
    const u16* b1 = bg1 + tap * 768;
    for (int kc = 0; kc < 768; kc += 64) {
#pragma unroll
      for (int p = 0; p < 2; ++p) {
        const int kk = kc + 32 * p;
        gload16(a0 + kk, &As[p][w * 1024]);
        gload16(a1 + kk, &As[p][w * 1024 + 512]);
        gload16(b0 + kk, &Bs[p][w * 1024]);
        gload16(b1 + kk, &Bs[p][w * 1024 + 512]);
      }
      __syncthreads();
#pragma unroll
      for (int p = 0; p < 2; ++p) {
        bf16x8 af[4], bf[4];
#pragma unroll
        for (int i = 0; i < 4; ++i) af[i] = *(const bf16x8*)&As[p][abase + i * 16 * 32];
#pragma unroll
        for (int j = 0; j < 4; ++j) bf[j] = *(const bf16x8*)&Bs[p][bbase + j * 16 * 32];
#pragma unroll
        for (int i = 0; i < 4; ++i)
#pragma unroll
          for (int j = 0; j < 4; ++j)
            acc[i][j] = __builtin_amdgcn_mfma_f32_16x16x32_bf16(af[i], bf[j], acc[i][j], 0, 0, 0);
      }
      __syncthreads();
    }
  }

  const int mw = m0 + wy * 64, nw = n0 + wx * 64;
#pragma unroll
  for (int i = 0; i < 4; ++i) {
#pragma unroll
    for (int j = 0; j < 4; ++j) {
      const int col = nw + j * 16 + lane15;
      const float bv = cbias[col];
#pragma unroll
      for (int r = 0; r < 4; ++r) {
        const int row = mw + i * 16 + quad * 4 + r;
        const size_t idx = (size_t)row * 768 + col;
        const float nz = z[idx] + acc[i][j][r] + bv;
        z[idx] = nz;
        zb[idx] = f2bf(nz);
      }
    }
  }
}

// ==================== encoder: patch-embed MFMA (fp32->bf16 staging, runs once) ====================
__global__ __launch_bounds__(256) void encoder_mfma_kernel(
    const float* __restrict__ x, const float* __restrict__ ew,
    const float* __restrict__ eb, float* __restrict__ z) {
  __shared__ u16 As[128 * 32];
  __shared__ u16 Bs[128 * 32];
  const int m0 = blockIdx.x * 128, n0 = blockIdx.y * 128;
  const int tid = threadIdx.x;
  const int lane = tid & 63, w = tid >> 6;
  const int lane15 = lane & 15, quad = lane >> 4;
  const int srow = tid >> 1, half = tid & 1;
  const int arow = m0 + srow;
  const int frame = arow >> 8, pix = arow & 255, hh = pix >> 4, ww = pix & 15;

  f32x4 acc[4][4] = {};
  const int wy = w >> 1, wx = w & 1;
  const int ar_base = (wy * 64 + lane15) * 32 + quad * 8;
  const int br_base = (wx * 64 + lane15) * 32 + quad * 8;

  for (int k0 = 0; k0 < 1024; k0 += 32) {
    const int gk = k0 + half * 16;
    const int c = gk >> 8, ph = (gk >> 4) & 15;
    const float* ax = x + (((size_t)(frame * 4 + c) * 256 + hh * 16 + ph) * 256 + ww * 16);
    const float* bx = ew + (size_t)(n0 + srow) * 1024 + gk;
    u16 ta[16], tb[16];
#pragma unroll
    for (int j = 0; j < 4; ++j) {
      const float4 va = *(const float4*)(ax + j * 4);
      const float4 vb = *(const float4*)(bx + j * 4);
      ta[j * 4 + 0] = f2bf(va.x); ta[j * 4 + 1] = f2bf(va.y);
      ta[j * 4 + 2] = f2bf(va.z); ta[j * 4 + 3] = f2bf(va.w);
      tb[j * 4 + 0] = f2bf(vb.x); tb[j * 4 + 1] = f2bf(vb.y);
      tb[j * 4 + 2] = f2bf(vb.z); tb[j * 4 + 3] = f2bf(vb.w);
    }
    __syncthreads();
    *(uint4*)&As[srow * 32 + half * 16] = *(uint4*)ta;
    *(uint4*)&As[srow * 32 + half * 16 + 8] = *(uint4*)(ta + 8);
    *(uint4*)&Bs[srow * 32 + half * 16] = *(uint4*)tb;
    *(uint4*)&Bs[srow * 32 + half * 16 + 8] = *(uint4*)(tb + 8);
    __syncthreads();
    bf16x8 af[4], bfv[4];
#pragma unroll
    for (int i = 0; i < 4; ++i) af[i] = *(const bf16x8*)&As[ar_base + i * 16 * 32];
#pragma unroll
    for (int j = 0; j < 4; ++j) bfv[j] = *(const bf16x8*)&Bs[br_base + j * 16 * 32];
#pragma unroll
    for (int i = 0; i < 4; ++i)
#pragma unroll
      for (int j = 0; j < 4; ++j)
        acc[i][j] = __builtin_amdgcn_mfma_f32_16x16x32_bf16(af[i], bfv[j], acc[i][j], 0, 0, 0);
  }

  const int mw = m0 + wy * 64, nw = n0 + wx * 64;
#pragma unroll
  for (int i = 0; i < 4; ++i)
#pragma unroll
    for (int j = 0; j < 4; ++j) {
      const int col = nw + j * 16 + lane15;
      const float bv = eb[col];
#pragma unroll
      for (int r = 0; r < 4; ++r) {
        const int row = mw + i * 16 + quad * 4 + r;
        z[(size_t)row * 768 + col] = acc[i][j][r] + bv;
      }
    }
}

// ==================== weight prep ====================
__global__ __launch_bounds__(256) void expand_kernel(
    const float* __restrict__ Wre, const float* __restrict__ Wim,
    int ldw, int Kc, int Nc, u16* __restrict__ Wt) {
  __shared__ float tile[32][33];
  const int k0 = blockIdx.x * 32, n0 = blockIdx.y * 32;
  const bool khi = k0 >= Kc, nhi = n0 >= Nc;
  const float* src = (khi != nhi) ? Wim : Wre;
  const float sgn = (!nhi && khi) ? -1.0f : 1.0f;
  const int sk = k0 - (khi ? Kc : 0), sn = n0 - (nhi ? Nc : 0);
  const int c = threadIdx.x & 31, r8 = threadIdx.x >> 5;
  for (int r = r8; r < 32; r += 8)
    tile[r][c] = src[(size_t)(sk + r) * ldw + sn + c];
  __syncthreads();
  const int twoK = 2 * Kc;
  for (int r = r8; r < 32; r += 8)
    Wt[(size_t)(n0 + r) * twoK + k0 + c] = f2bf(sgn * tile[c][r]);
}

__global__ __launch_bounds__(256) void reorder_cw_kernel(
    const float* __restrict__ cwl, u16* __restrict__ Btc) {
  __shared__ float buf[6912];
  const int o = blockIdx.x;
  const float* src = cwl + (size_t)o * 6912;
  for (int i = threadIdx.x; i < 6912; i += 256) buf[i] = src[i];
  __syncthreads();
  u16* dst = Btc + (size_t)o * 6912;
  for (int i = threadIdx.x; i < 6912; i += 256) {
    const int tap = i / 768, cc = i - tap * 768;
    dst[i] = f2bf(buf[cc * 9 + tap]);
  }
}

__global__ __launch_bounds__(256) void cast_bf16_kernel(
    const float* __restrict__ in, u16* __restrict__ out, int n) {
  const int g = blockIdx.x * 256 + threadIdx.x;
  if (g < n) out[g] = f2bf(in[g]);
}

// ==================== LayerNorm (contiguous 768) ====================
template <bool HALO>
__global__ __launch_bounds__(192) void ln_kernel(
    const float* __restrict__ in, const float* __restrict__ g,
    const float* __restrict__ b, u16* __restrict__ out) {
  const int row = blockIdx.x, tid = threadIdx.x;
  const float4 v = *(const float4*)(in + (size_t)row * 768 + tid * 4);
  float s = v.x + v.y + v.z + v.w;
  float q = v.x * v.x + v.y * v.y + v.z * v.z + v.w * v.w;
#pragma unroll
  for (int off = 32; off > 0; off >>= 1) {
    s += __shfl_down(s, off);
    q += __shfl_down(q, off);
  }
  __shared__ float rs[3], rq[3];
  if ((tid & 63) == 0) { rs[tid >> 6] = s; rq[tid >> 6] = q; }
  __syncthreads();
  const float S = rs[0] + rs[1] + rs[2], Q = rq[0] + rq[1] + rq[2];
  const float mean = S * (1.0f / 768.0f);
  const float inv = rsqrtf(Q * (1.0f / 768.0f) - mean * mean + 1e-5f);
  const float4 gv = *(const float4*)(g + tid * 4);
  const float4 bv = *(const float4*)(b + tid * 4);
  u16 p[4];
  p[0] = f2bf((v.x - mean) * inv * gv.x + bv.x);
  p[1] = f2bf((v.y - mean) * inv * gv.y + bv.y);
  p[2] = f2bf((v.z - mean) * inv * gv.z + bv.z);
  p[3] = f2bf((v.w - mean) * inv * gv.w + bv.w);
  size_t base;
  if (HALO) {
    const int f = row >> 8, pp = row & 255, h = pp >> 4, ww = pp & 15;
    base = ((size_t)f * 324 + (h + 1) * 18 + ww + 1) * 768;
  } else {
    base = (size_t)row * 768;
  }
  *(uint2*)(out + base + tid * 4) = *(uint2*)p;
}

// ==================== mean over 256 pixels ====================
__global__ __launch_bounds__(768) void mean_kernel(
    const float* __restrict__ eig, float* __restrict__ mr, float* __restrict__ mi) {
  const int f = blockIdx.x, c = threadIdx.x;
  const float* p = eig + (size_t)f * 256 * 768 + c;
  float s0 = 0.f, s1 = 0.f, s2 = 0.f, s3 = 0.f;
  for (int px = 0; px < 256; px += 4) {
    s0 += p[(size_t)px * 768];
    s1 += p[(size_t)(px + 1) * 768];
    s2 += p[(size_t)(px + 2) * 768];
    s3 += p[(size_t)(px + 3) * 768];
  }
  const float tot = (s0 + s1 + s2 + s3) * (1.0f / 256.0f);
  if (c < 384) mr[f * 384 + c] = tot;
  else         mi[f * 384 + c - 384] = tot;
}

// ==================== flux scan + operator precompute ====================
__global__ __launch_bounds__(384) void flux_kernel(
    const float* __restrict__ dt, const float* __restrict__ lamf,
    const float* __restrict__ nu, const float* __restrict__ omega,
    const float* __restrict__ mr, const float* __restrict__ mi,
    float* __restrict__ fluxr, float* __restrict__ fluxi,
    float* __restrict__ opdr, float* __restrict__ opdi,
    float* __restrict__ opfr, float* __restrict__ opfi) {
  const int b = blockIdx.x;
  const int d = threadIdx.x;
  const float sp = softplus_f(lamf[d]);
  float lre = -softplus_f(nu[d]);
  lre = fmaxf(lre, -5.0f);
  const float lim = omega[d];
  const float den = lre * lre + lim * lim;
  float fr = 0.f, fi = 0.f;
  for (int t = 0; t < 12; ++t) {
    const float dtv = dt[b * 12 + t];
    const int idx = (b * 12 + t) * 384 + d;
    const float A = expf(-sp * dtv);
    fr = A * fr + mr[idx] * dtv;
    fi = A * fi + mi[idx] * dtv;
    fluxr[idx] = fr; fluxi[idx] = fi;
    const float ed = expf(lre * dtv);
    const float odr = ed * cosf(lim * dtv);
    const float odi = ed * sinf(lim * dtv);
    opdr[idx] = odr; opdi[idx] = odi;
    const float nr_ = odr - 1.0f, ni_ = odi;
    opfr[idx] = (nr_ * lre + ni_ * lim) / den;
    opfi[idx] = (ni_ * lre - nr_ * lim) / den;
  }
}

// ==================== small fp32 complex GEMM + gate-product epilogue ====================
#define SBM 64
#define SBN 64
#define SBK 32
__global__ __launch_bounds__(256) void cgemm_src_kernel(
    const float* __restrict__ Ar, const float* __restrict__ Ai, int lda,
    const float* __restrict__ Wr, const float* __restrict__ Wi, int ldw,
    const float* __restrict__ Wg,
    float* __restrict__ G, float* __restrict__ SGr, float* __restrict__ SGi,
    int ldc, int M, int K) {
  __shared__ float Asr[SBK][SBM], Asi[SBK][SBM];
  __shared__ float Wsr[SBK][SBN], Wsi[SBK][SBN];
  const int m0 = blockIdx.x * SBM;
  const int n0 = blockIdx.y * SBN;
  const int tid = threadIdx.x;
  const int tn = tid & 15, tm = tid >> 4;
  float accr[4][4] = {}, acci[4][4] = {};
  for (int k0 = 0; k0 < K; k0 += SBK) {
    for (int s = tid; s < 512; s += 256) {
      {
        int r = s >> 3, kk = (s & 7) << 2;
        int row = m0 + r;
        float4 vr = {0.f, 0.f, 0.f, 0.f}, vi = {0.f, 0.f, 0.f, 0.f};
        if (row < M) {
          vr = *(const float4*)(Ar + (size_t)row * lda + k0 + kk);
          vi = *(const float4*)(Ai + (size_t)row * lda + k0 + kk);
        }
        Asr[kk + 0][r] = vr.x; Asr[kk + 1][r] = vr.y; Asr[kk + 2][r] = vr.z; Asr[kk + 3][r] = vr.w;
        Asi[kk + 0][r] = vi.x; Asi[kk + 1][r] = vi.y; Asi[kk + 2][r] = vi.z; Asi[kk + 3][r] = vi.w;
      }
      {
        int wr_ = s >> 4, wc = (s & 15) << 2;
        *(float4*)&Wsr[wr_][wc] = *(const float4*)(Wr + (size_t)(k0 + wr_) * ldw + n0 + wc);
        *(float4*)&Wsi[wr_][wc] = *(const float4*)(Wi + (size_t)(k0 + wr_) * ldw + n0 + wc);
      }
    }
    __syncthreads();
#pragma unroll
    for (int kk = 0; kk < SBK; ++kk) {
      float4 ar4 = *(const float4*)&Asr[kk][tm << 2];
      float4 ai4 = *(const float4*)&Asi[kk][tm << 2];
      float4 wr4 = *(const float4*)&Wsr[kk][tn << 2];
      float4 wi4 = *(const float4*)&Wsi[kk][tn << 2];
      float ar[4] = {ar4.x, ar4.y, ar4.z, ar4.w};
      float ai[4] = {ai4.x, ai4.y, ai4.z, ai4.w};
      float wr[4] = {wr4.x, wr4.y, wr4.z, wr4.w};
      float wi[4] = {wi4.x, wi4.y, wi4.z, wi4.w};
#pragma unroll
      for (int i = 0; i < 4; ++i)
#pragma unroll
        for (int j = 0; j < 4; ++j) {
          accr[i][j] = fmaf(ar[i], wr[j], accr[i][j]);
          accr[i][j] = fmaf(-ai[i], wi[j], accr[i][j]);
          acci[i][j] = fmaf(ar[i], wi[j], acci[i][j]);
          acci[i][j] = fmaf(ai[i], wr[j], acci[i][j]);
        }
    }
    __syncthreads();
  }
#pragma unroll
  for (int i = 0; i < 4; ++i) {
    int row = m0 + (tm << 2) + i;
    if (row >= M) continue;
#pragma unroll
    for (int j = 0; j < 4; ++j) {
      int col = n0 + (tn << 2) + j;
      size_t idx = (size_t)row * ldc + col;
      const float gate = 1.0f / (1.0f + expf(-Ar[idx] * Wg[col]));
      G[idx] = gate;
      SGr[idx] = accr[i][j] * (1.0f - gate);
      SGi[idx] = acci[i][j] * (1.0f - gate);
    }
  }
}

// ==================== fused forcing + u_out pscan -> bf16 ub ====================
__global__ __launch_bounds__(256) void pscan_fused_kernel(
    const float* __restrict__ eig,
    const float* __restrict__ Gv,
    const float* __restrict__ SGr, const float* __restrict__ SGi,
    const float* __restrict__ opfr, const float* __restrict__ opfi,
    const float* __restrict__ opdr, const float* __restrict__ opdi,
    u16* __restrict__ ub) {
  const int g = blockIdx.x * 256 + threadIdx.x;
  if (g >= 4 * 256 * 384) return;
  const int d = g % 384;
  const int pix = (g / 384) & 255;
  const int b = g / (384 * 256);
  float ur = 0.f, ui = 0.f;
  for (int t = 0; t < 12; ++t) {
    const int frame = b * 12 + t;
    const size_t idx = ((size_t)frame * 256 + pix) * 768 + d;
    const int fidx = frame * 384 + d;
    const float G = Gv[fidx];
    const float fr = eig[idx] * G + SGr[fidx];
    const float fi = eig[idx + 384] * G + SGi[fidx];
    const float pr = opfr[fidx], pi = opfi[fidx];
    const float utr = fr * pr - fi * pi;
    const float uti = fr * pi + fi * pr;
    const float ar = opdr[fidx], ai = opdi[fidx];
    const float nr = ar * ur - ai * ui + utr;
    const float ni = ar * ui + ai * ur + uti;
    ub[idx] = f2bf(nr); ub[idx + 384] = f2bf(ni);
    ur = nr; ui = ni;
  }
}

extern "C" void kernel_launch(void* const* d_in, const int* in_sizes, int n_in,
                              void* d_out, int out_size, void* d_ws, size_t ws_size,
                              hipStream_t stream) {
  const float* x        = (const float*)d_in[0];
  const float* dt       = (const float*)d_in[1];
  const float* enc_w    = (const float*)d_in[2];
  const float* enc_b    = (const float*)d_in[3];
  const float* ns_g     = (const float*)d_in[4];
  const float* ns_b     = (const float*)d_in[5];
  const float* cw       = (const float*)d_in[6];
  const float* cb       = (const float*)d_in[7];
  const float* nt_g     = (const float*)d_in[8];
  const float* nt_b     = (const float*)d_in[9];
  const float* E_re     = (const float*)d_in[10];
  const float* E_im     = (const float*)d_in[11];
  const float* Ei_re    = (const float*)d_in[12];
  const float* Ei_im    = (const float*)d_in[13];
  const float* lam_flux = (const float*)d_in[14];
  const float* Ws_re    = (const float*)d_in[15];
  const float* Ws_im    = (const float*)d_in[16];
  const float* Wg       = (const float*)d_in[17];
  const float* nu       = (const float*)d_in[18];
  const float* omega    = (const float*)d_in[19];
  const float* w1_re    = (const float*)d_in[20];
  const float* w1_im    = (const float*)d_in[21];
  const float* w2_re    = (const float*)d_in[22];
  const float* w2_im    = (const float*)d_in[23];
  const float* dec_w    = (const float*)d_in[24];
  const float* dec_b    = (const float*)d_in[25];
  float* out = (float*)d_out;

  const size_t NPF = 12288ull * 768;        // 9,437,184
  const size_t XNP = 48ull * 324 * 768;     // 11,943,936 (halo-padded plane)
  const size_t SM = 48ull * 384;

  float* z   = (float*)d_ws;                 // [12288][768] fp32 residual master
  float* eig = z + NPF;                      // fp32; aliased by h1b
  float* df  = eig + NPF;                    // fp32; aliased by zb
  u16* xnp   = (u16*)(df + NPF);             // halo xnbp / flat xnb / ub
  u16* Btc   = xnp + XNP;                    // [768][6912]
  u16* Et    = Btc + 5308416;                // [768][768]
  u16* Eit   = Et + 589824;
  u16* W1t   = Eit + 589824;                 // 2 chunks x [1536][768]
  u16* W2t   = W1t + 2359296;                // 2 chunks x [768][1536]
  u16* dwt   = W2t + 2359296;                // [1024][768]
  float* sm  = (float*)(dwt + 786432);
  float* mr    = sm;            float* mi    = mr + SM;
  float* fluxr = mi + SM;       float* fluxi = fluxr + SM;
  float* opdr  = fluxi + SM;    float* opdi  = opdr + SM;
  float* opfr  = opdi + SM;     float* opfi  = opfr + SM;
  float* Gv    = opfi + SM;     float* SGr   = Gv + SM;
  float* SGi   = SGr + SM;

  const size_t need = ((char*)(SGi + SM)) - ((char*)d_ws);
  if (ws_size < need) return;

  u16* zb  = (u16*)df;    // bf16 shadow of z (df dead at that point)
  u16* h1b = (u16*)eig;   // FFN hidden chunk [12288][1536] bf16 (eig dead after pscan)

  cast_bf16_kernel<<<(786432 + 255) / 256, 256, 0, stream>>>(dec_w, dwt, 786432);
  encoder_mfma_kernel<<<dim3(96, 6), 256, 0, stream>>>(x, enc_w, enc_b, z);

  for (int l = 0; l < 4; ++l) {
    const size_t DD = 384ull * 384, DF = 384ull * 1536;
    hipMemsetAsync(xnp, 0, XNP * sizeof(u16), stream);  // zero halo borders
    reorder_cw_kernel<<<768, 256, 0, stream>>>(cw + (size_t)l * 768 * 768 * 9, Btc);
    expand_kernel<<<dim3(24, 24), 256, 0, stream>>>(E_re + l * DD, E_im + l * DD, 384, 384, 384, Et);
    expand_kernel<<<dim3(24, 24), 256, 0, stream>>>(Ei_re + l * DD, Ei_im + l * DD, 384, 384, 384, Eit);
    for (int ch = 0; ch < 2; ++ch) {
      expand_kernel<<<dim3(24, 48), 256, 0, stream>>>(
          w1_re + l * DF + ch * 768, w1_im + l * DF + ch * 768, 1536, 384, 768, W1t + (size_t)ch * 1179648);
      expand_kernel<<<dim3(48, 24), 256, 0, stream>>>(
          w2_re + l * DF + (size_t)ch * 768 * 384, w2_im + l * DF + (size_t)ch * 768 * 384, 384, 768, 384,
          W2t + (size_t)ch * 1179648);
    }

    ln_kernel<true><<<12288, 192, 0, stream>>>(z, ns_g + l * 768, ns_b + l * 768, xnp);
    conv_mfma_kernel<<<dim3(96, 6), 256, 0, stream>>>(xnp, Btc, cb + l * 768, z, zb);
    gemm_kernel<64, 0><<<dim3(96, 12), 256, 0, stream>>>(zb, Et, 768, 768, eig, nullptr, nullptr, nullptr);
    mean_kernel<<<48, 768, 0, stream>>>(eig, mr, mi);
    flux_kernel<<<4, 384, 0, stream>>>(dt, lam_flux + l * 384, nu + l * 384, omega + l * 384,
                                       mr, mi, fluxr, fluxi, opdr, opdi, opfr, opfi);
    cgemm_src_kernel<<<dim3(1, 6), 256, 0, stream>>>(
        fluxr, fluxi, 384, Ws_re + l * DD, Ws_im + l * DD, 384,
        Wg + l * 384, Gv, SGr, SGi, 384, 48, 384);
    pscan_fused_kernel<<<1536, 256, 0, stream>>>(eig, Gv, SGr, SGi, opfr, opfi, opdr, opdi, xnp);
    gemm_kernel<64, 0><<<dim3(96, 12), 256, 0, stream>>>(xnp, Eit, 768, 768, df, nullptr, nullptr, nullptr);
    ln_kernel<false><<<12288, 192, 0, stream>>>(df, nt_g + l * 768, nt_b + l * 768, xnp);
    for (int ch = 0; ch < 2; ++ch) {
      gemm_kernel<128, 1><<<dim3(96, 12), 256, 0, stream>>>(
          xnp, W1t + (size_t)ch * 1179648, 768, 1536, nullptr, h1b, nullptr, nullptr);
      if (ch == 0) {
        gemm_kernel<64, 4><<<dim3(96, 12), 256, 0, stream>>>(
            h1b, W2t, 1536, 768, z, nullptr, nullptr, df);
      } else if (l < 3) {
        gemm_kernel<64, 2><<<dim3(96, 12), 256, 0, stream>>>(
            h1b, W2t + 1179648, 1536, 768, z, nullptr, nullptr, nullptr);
      } else {
        gemm_kernel<64, 5><<<dim3(96, 12), 256, 0, stream>>>(
            h1b, W2t + 1179648, 1536, 768, z, zb, nullptr, nullptr);
      }
    }
  }

  gemm_kernel<64, 3><<<dim3(96, 16), 256, 0, stream>>>(zb, dwt, 768, 0, out, nullptr, dec_b, nullptr);
}